// Round 1
// baseline (546.777 us; speedup 1.0000x reference)
//
#include <hip/hip_runtime.h>
#include <hip/hip_bf16.h>

typedef __hip_bfloat16 bf16;

__device__ __forceinline__ float lo16(unsigned u){ return __uint_as_float(u << 16); }
__device__ __forceinline__ float hi16(unsigned u){ return __uint_as_float(u & 0xffff0000u); }

// B=512, L=64, DDYN=16, DSTAT=8, H=512, C=1024, K=16, P=8, T=2, Q=3
#define Bn 512
#define Hn 512
#define Cn 1024
#define Kn 16
#define NBANK 50000
#define NIDPAD 50176   // 196*256, padded histogram size

__device__ __forceinline__ int clamp_id(int id){
    return (id < 0) ? 0 : ((id >= NBANK) ? (NBANK - 1) : id);
}

// ---------------- ws layout (floats), 8 MB total ----------------
// QRAW [512][512] @0        (normalized in place; later recycled as F1)
// G: three contiguous [512][512] slabs: LOCAL @262144, DONOR @524288, PROTO @786432
//    (DONOR+PROTO slabs double as REFS[524288] u32 during the sim phase)
// SIM  [512][1024] @1048576 (later recycled: first 512*512 = F2 accum)
// GATE [512][512] @1572864  (during sim phase: HIST/CURSOR/OFFS/CHPREF ints; re-zeroed after k_select)
// TR   [512][512] @1835008
#define QRAW_OFF 0
#define F1_OFF   0
#define G_OFF    262144
#define DONOR_OFF (G_OFF + 262144)
#define PROTO_OFF (G_OFF + 524288)
#define SIM_OFF  1048576
#define F2_OFF   1048576
#define GATE_OFF 1572864
#define TR_OFF   1835008
#define WS_FLOATS 2097152

// int offsets within the GATE slab (as int*)
#define HIST_I   0
#define CURSOR_I NIDPAD
#define OFFS_I   (2*NIDPAD)
#define CHPREF_I (2*NIDPAD + NIDPAD)   // 196 entries; total 150724 ints < 262144

// ============ K1: encoder -> local hidden into LOCAL slab; fused candidate histogram ============
__global__ __launch_bounds__(256) void k_enc(
    const float* __restrict__ seq, const float* __restrict__ mask, const float* __restrict__ stat,
    const float* __restrict__ W_seq, const float* __restrict__ W_stat, const float* __restrict__ b_enc,
    const int* __restrict__ cand32, float* __restrict__ ws)
{
    const int b = blockIdx.x, t = threadIdx.x;
    const int h0 = 2*t, h1 = 2*t + 1;

    // fused histogram of this batch row's 1024 candidate ids
    {
        const int c64 = ((cand32[1] | cand32[3] | cand32[5] | cand32[7]) == 0) ? 1 : 0;
        int* hist = (int*)(ws + GATE_OFF) + HIST_I;
        #pragma unroll
        for (int u = 0; u < 4; u++) {
            int idx = b*Cn + u*256 + t;
            atomicAdd(&hist[clamp_id(cand32[(size_t)idx << c64])], 1);
        }
    }

    __shared__ float s_pool[16], s_stat[8];
    if (t < 16) {
        float acc = 0.f, ms = 0.f;
        for (int l = 0; l < 64; l++) {
            float m = mask[b*64 + l];
            ms  += m;
            acc += seq[(b*64 + l)*16 + t] * m;
        }
        s_pool[t] = acc / fmaxf(ms, 1e-6f);
    } else if (t < 24) {
        s_stat[t - 16] = stat[b*8 + (t - 16)];
    }
    __syncthreads();
    float a0 = b_enc[h0], a1 = b_enc[h1];
    #pragma unroll
    for (int j = 0; j < 16; j++) {
        float2 wv = *(const float2*)(W_seq + j*Hn + h0);
        a0 += s_pool[j]*wv.x; a1 += s_pool[j]*wv.y;
    }
    #pragma unroll
    for (int j = 0; j < 8; j++) {
        float2 wv = *(const float2*)(W_stat + j*Hn + h0);
        a0 += s_stat[j]*wv.x; a1 += s_stat[j]*wv.y;
    }
    float* g = ws + G_OFF + (size_t)b*Hn;
    g[h0] = fmaxf(a0, 0.f); g[h1] = fmaxf(a1, 0.f);
}

// ============ K2: qraw += local @ W_q (split-K, atomic) ============
// grid (8 ct, 8 rt, 4 kz); tile 64r x 64c, K-slice 128; thread 4r x 4c
__global__ __launch_bounds__(256) void k_qgemm_sk(
    const float* __restrict__ W, const float* __restrict__ bias,
    const float* __restrict__ in, int in_stride, int in_off,
    float* __restrict__ outp)
{
    const int ct = blockIdx.x, rt = blockIdx.y, kz = blockIdx.z, t = threadIdx.x;
    __shared__ float lt[64][132];
    {   // stage 64 rows x 128 k
        int r = t >> 2, c0 = (t & 3)*32;
        const float* src = in + (size_t)(rt*64 + r)*in_stride + in_off + kz*128 + c0;
        #pragma unroll
        for (int i = 0; i < 8; i++)
            *(float4*)&lt[r][c0 + i*4] = *(const float4*)(src + i*4);
    }
    __syncthreads();
    const int col0 = ct*64 + (t & 15)*4, rbase = (t >> 4)*4;
    float acc[4][4];
    if (kz == 0) {
        float4 bv = *(const float4*)(bias + col0);
        #pragma unroll
        for (int i = 0; i < 4; i++) { acc[i][0]=bv.x; acc[i][1]=bv.y; acc[i][2]=bv.z; acc[i][3]=bv.w; }
    } else {
        #pragma unroll
        for (int i = 0; i < 4; i++) { acc[i][0]=0; acc[i][1]=0; acc[i][2]=0; acc[i][3]=0; }
    }
    const float* wp = W + (size_t)(kz*128)*Hn + col0;
    #pragma unroll 4
    for (int k = 0; k < 128; k++) {
        float4 wv = *(const float4*)(wp + (size_t)k*Hn);
        #pragma unroll
        for (int i = 0; i < 4; i++) {
            float a = lt[rbase + i][k];
            acc[i][0] += a*wv.x; acc[i][1] += a*wv.y; acc[i][2] += a*wv.z; acc[i][3] += a*wv.w;
        }
    }
    #pragma unroll
    for (int i = 0; i < 4; i++) {
        float* op = outp + (size_t)(rt*64 + rbase + i)*Hn + col0;
        atomicAdd(op+0, acc[i][0]); atomicAdd(op+1, acc[i][1]);
        atomicAdd(op+2, acc[i][2]); atomicAdd(op+3, acc[i][3]);
    }
}

// ============ K2b: normalize QRAW rows in place (bit-identical to old per-use normalization) ============
__global__ __launch_bounds__(64) void k_qnorm(float* __restrict__ ws)
{
    const int b = blockIdx.x, lane = threadIdx.x;
    float* qr = ws + QRAW_OFF + (size_t)b*Hn + lane*8;
    float4 qa = *(const float4*)qr, qb = *(const float4*)(qr + 4);
    float ss = qa.x*qa.x + qa.y*qa.y + qa.z*qa.z + qa.w*qa.w
             + qb.x*qb.x + qb.y*qb.y + qb.z*qb.z + qb.w*qb.w;
    #pragma unroll
    for (int o = 32; o; o >>= 1) ss += __shfl_xor(ss, o);
    float inv = 1.f / fmaxf(sqrtf(ss), 1e-12f);
    qa.x *= inv; qa.y *= inv; qa.z *= inv; qa.w *= inv;
    qb.x *= inv; qb.y *= inv; qb.z *= inv; qb.w *= inv;
    *(float4*)qr = qa; *(float4*)(qr + 4) = qb;
}

// ============ K3a: per-chunk exclusive scan of histogram (chunk=256) ============
__global__ __launch_bounds__(256) void k_scanA(
    const int* __restrict__ hist, int* __restrict__ offs, int* __restrict__ chsum)
{
    __shared__ int s[256];
    const int t = threadIdx.x, g = blockIdx.x*256 + t;
    const int v = hist[g];
    s[t] = v; __syncthreads();
    #pragma unroll
    for (int off = 1; off < 256; off <<= 1) {
        int x = (t >= off) ? s[t - off] : 0;
        __syncthreads();
        s[t] += x;
        __syncthreads();
    }
    offs[g] = s[t] - v;                 // exclusive within chunk
    if (t == 255) chsum[blockIdx.x] = s[255];
}

// ============ K3b: exclusive scan of 196 chunk sums (in place) ============
__global__ __launch_bounds__(256) void k_scanB(int* __restrict__ chsum)
{
    __shared__ int s[256];
    const int t = threadIdx.x;
    const int v = (t < 196) ? chsum[t] : 0;
    s[t] = v; __syncthreads();
    #pragma unroll
    for (int off = 1; off < 256; off <<= 1) {
        int x = (t >= off) ? s[t - off] : 0;
        __syncthreads();
        s[t] += x;
        __syncthreads();
    }
    if (t < 196) chsum[t] = s[t] - v;   // exclusive chunk prefix
}

// ============ K3c: scatter (b,c) refs into id buckets ============
__global__ __launch_bounds__(256) void k_scatter(
    const int* __restrict__ cand32, int* __restrict__ cursor,
    const int* __restrict__ offs, const int* __restrict__ chpref,
    unsigned* __restrict__ refs)
{
    const int i = blockIdx.x*256 + threadIdx.x;   // i = b*1024 + c, 524288 total
    const int c64 = ((cand32[1] | cand32[3] | cand32[5] | cand32[7]) == 0) ? 1 : 0;
    const int id = clamp_id(cand32[(size_t)i << c64]);
    const int pos = atomicAdd(&cursor[id], 1);
    refs[offs[id] + chpref[id >> 8] + pos] = (unsigned)i;
}

// ============ K3d: inverted-index sim — one wave per bank id ============
// Key (2KB) loaded once per id (sequential stream over the bank);
// referencing queries are L2-resident (QRAW = 1MB). sim index == packed ref.
__global__ __launch_bounds__(256) void k_dotinv(
    const float* __restrict__ bank_keys, const unsigned* __restrict__ refs,
    const int* __restrict__ offs, const int* __restrict__ chpref,
    float* __restrict__ ws)
{
    const int id = blockIdx.x*4 + (threadIdx.x >> 6);   // grid 12500*4 = 50000 exactly
    const int lane = threadIdx.x & 63;
    const int start = offs[id]     + chpref[id >> 8];
    const int end   = offs[id + 1] + chpref[(id + 1) >> 8];
    if (start >= end) return;

    const float* kp = bank_keys + (size_t)id*Hn + lane*8;
    float4 ka = *(const float4*)kp, kb = *(const float4*)(kp + 4);
    const float* qbase = ws + QRAW_OFF;
    float* simw = ws + SIM_OFF;

    for (int r = start; r < end; r += 4) {
        const int nn = end - r;
        unsigned rv0 = refs[r];
        unsigned rv1 = refs[nn > 1 ? r + 1 : r];
        unsigned rv2 = refs[nn > 2 ? r + 2 : r];
        unsigned rv3 = refs[nn > 3 ? r + 3 : r];
        const float* q0 = qbase + (size_t)(rv0 >> 10)*Hn + lane*8;
        const float* q1 = qbase + (size_t)(rv1 >> 10)*Hn + lane*8;
        const float* q2 = qbase + (size_t)(rv2 >> 10)*Hn + lane*8;
        const float* q3 = qbase + (size_t)(rv3 >> 10)*Hn + lane*8;
        float4 a0 = *(const float4*)q0, b0 = *(const float4*)(q0 + 4);
        float4 a1 = *(const float4*)q1, b1 = *(const float4*)(q1 + 4);
        float4 a2 = *(const float4*)q2, b2 = *(const float4*)(q2 + 4);
        float4 a3 = *(const float4*)q3, b3 = *(const float4*)(q3 + 4);
        float s0 = ka.x*a0.x + ka.y*a0.y + ka.z*a0.z + ka.w*a0.w
                 + kb.x*b0.x + kb.y*b0.y + kb.z*b0.z + kb.w*b0.w;
        float s1 = ka.x*a1.x + ka.y*a1.y + ka.z*a1.z + ka.w*a1.w
                 + kb.x*b1.x + kb.y*b1.y + kb.z*b1.z + kb.w*b1.w;
        float s2 = ka.x*a2.x + ka.y*a2.y + ka.z*a2.z + ka.w*a2.w
                 + kb.x*b2.x + kb.y*b2.y + kb.z*b2.z + kb.w*b2.w;
        float s3 = ka.x*a3.x + ka.y*a3.y + ka.z*a3.z + ka.w*a3.w
                 + kb.x*b3.x + kb.y*b3.y + kb.z*b3.z + kb.w*b3.w;
        #pragma unroll
        for (int o = 32; o; o >>= 1) {
            s0 += __shfl_xor(s0, o); s1 += __shfl_xor(s1, o);
            s2 += __shfl_xor(s2, o); s3 += __shfl_xor(s3, o);
        }
        if (lane == 0) {
            simw[rv0] = s0;
            if (nn > 1) simw[rv1] = s1;
            if (nn > 2) simw[rv2] = s2;
            if (nn > 3) simw[rv3] = s3;
        }
    }
}

// ============ K4: top-16 + softmax + donor + proto ============
__global__ __launch_bounds__(256) void k_select(
    const float* __restrict__ bank_values, const int* __restrict__ cand32,
    const float* __restrict__ proto, float* __restrict__ ws)
{
    const int b = blockIdx.x, t = threadIdx.x;
    const int w = t >> 6, lane = t & 63;
    const int h0 = 2*t, h1 = 2*t + 1;
    const int c64 = ((cand32[1] | cand32[3] | cand32[5] | cand32[7]) == 0) ? 1 : 0;

    __shared__ __align__(16) float s_sim[Cn];
    __shared__ float s_bv[4]; __shared__ int s_bi[4];
    __shared__ float s_topv[Kn]; __shared__ int s_sel[Kn];
    __shared__ float s_w[Kn];
    __shared__ float s_score[8], s_pw[8];

    *(float4*)&s_sim[t*4] = *(const float4*)(ws + SIM_OFF + (size_t)b*Cn + t*4);

    // QRAW is pre-normalized: load directly (same bits as the old in-kernel renorm)
    const float* qr = ws + QRAW_OFF + (size_t)b*Hn + lane*8;
    float4 qa = *(const float4*)qr, qb = *(const float4*)(qr + 4);
    float qv[8] = {qa.x, qa.y, qa.z, qa.w, qb.x, qb.y, qb.z, qb.w};
    __syncthreads();

    for (int k = 0; k < Kn; k++) {
        float best = -1e30f; int bi = 0x7fffffff;
        for (int i = t; i < Cn; i += 256) {
            float v = s_sim[i];
            if (v > best || (v == best && i < bi)) { best = v; bi = i; }
        }
        #pragma unroll
        for (int o = 32; o; o >>= 1) {
            float ov = __shfl_xor(best, o); int oi = __shfl_xor(bi, o);
            if (ov > best || (ov == best && oi < bi)) { best = ov; bi = oi; }
        }
        if (lane == 0) { s_bv[w] = best; s_bi[w] = bi; }
        __syncthreads();
        if (t == 0) {
            float bv = s_bv[0]; int bbi = s_bi[0];
            for (int x = 1; x < 4; x++)
                if (s_bv[x] > bv || (s_bv[x] == bv && s_bi[x] < bbi)) { bv = s_bv[x]; bbi = s_bi[x]; }
            if (bbi < 0 || bbi >= Cn) bbi = 0;
            s_topv[k] = bv; s_sel[k] = bbi; s_sim[bbi] = -1e30f;
        }
        __syncthreads();
    }

    if (t == 0) {
        float m = s_topv[0];
        float e[Kn], ssum = 0.f;
        for (int k = 0; k < Kn; k++) { e[k] = __expf((s_topv[k] - m) * 5.0f); ssum += e[k]; }
        float inv = 1.f / ssum;
        for (int k = 0; k < Kn; k++) s_w[k] = e[k] * inv;
    }
    for (int p = w; p < 8; p += 4) {
        const float* pp = proto + (size_t)p*Hn + lane*8;
        float4 pa = *(const float4*)pp, pb = *(const float4*)(pp + 4);
        float f[8] = {pa.x, pa.y, pa.z, pa.w, pb.x, pb.y, pb.z, pb.w};
        float dq = 0.f, sq = 0.f;
        #pragma unroll
        for (int i = 0; i < 8; i++) { dq += f[i]*qv[i]; sq += f[i]*f[i]; }
        #pragma unroll
        for (int o = 32; o; o >>= 1) { dq += __shfl_xor(dq, o); sq += __shfl_xor(sq, o); }
        if (lane == 0) s_score[p] = dq / fmaxf(sqrtf(sq), 1e-12f);
    }
    __syncthreads();
    if (t == 0) {
        float m = s_score[0];
        for (int p = 1; p < 8; p++) m = fmaxf(m, s_score[p]);
        float e[8], ssum = 0.f;
        for (int p = 0; p < 8; p++) { e[p] = __expf(s_score[p] - m); ssum += e[p]; }
        float inv = 1.f / ssum;
        for (int p = 0; p < 8; p++) s_pw[p] = e[p] * inv;
    }
    __syncthreads();

    {
        float a0 = 0.f, a1 = 0.f;
        #pragma unroll
        for (int k = 0; k < Kn; k++) {
            int id = clamp_id(cand32[(size_t)(b*Cn + s_sel[k]) << c64]);
            float2 v = *(const float2*)(bank_values + (size_t)id*Hn + h0);
            a0 += s_w[k]*v.x; a1 += s_w[k]*v.y;
        }
        float* gd = ws + DONOR_OFF + (size_t)b*Hn;
        gd[h0] = a0; gd[h1] = a1;
    }
    {
        float a0 = 0.f, a1 = 0.f;
        #pragma unroll
        for (int p = 0; p < 8; p++) {
            float2 v = *(const float2*)(proto + (size_t)p*Hn + h0);
            a0 += s_pw[p]*v.x; a1 += s_pw[p]*v.y;
        }
        float* gp = ws + PROTO_OFF + (size_t)b*Hn;
        gp[h0] = a0; gp[h1] = a1;
    }
}

// ============ K5: gate/tr accum (split-K, atomic) ============
// grid (4 ct, 16 rt, 10 z): z<6 -> W_gate slice z (K=256), z>=6 -> W_tr slice z-6
// input slabs: LOCAL|DONOR|PROTO each [512][512], contiguous
__global__ __launch_bounds__(256) void k_gatetr_sk(
    const float* __restrict__ W_tr, const float* __restrict__ b_tr,
    const float* __restrict__ W_gate, const float* __restrict__ b_gate,
    float* __restrict__ ws)
{
    const int ct = blockIdx.x, rt = blockIdx.y, z = blockIdx.z, t = threadIdx.x;
    const int isGate = (z < 6);
    const int slice = isGate ? z : (z - 6);
    const float* W  = isGate ? W_gate : W_tr;
    const int gcol = isGate ? slice*256 : 512 + slice*256;   // global input column
    const float* srcbase = ws + G_OFF + (size_t)(gcol >> 9)*262144 + (gcol & 511);
    float* outp = ws + (isGate ? GATE_OFF : TR_OFF);

    __shared__ float lt[32][260];
    {   // stage 32 rows x 256 k
        int r = t >> 3, c0 = (t & 7)*32;
        const float* src = srcbase + (size_t)(rt*32 + r)*Hn + c0;
        #pragma unroll
        for (int i = 0; i < 8; i++)
            *(float4*)&lt[r][c0 + i*4] = *(const float4*)(src + i*4);
    }
    __syncthreads();
    const int col0 = ct*128 + (t & 31)*4, rbase = (t >> 5)*4;
    float acc[4][4];
    if (slice == 0) {
        const float* bias = isGate ? b_gate : b_tr;
        float4 bv = *(const float4*)(bias + col0);
        #pragma unroll
        for (int i = 0; i < 4; i++) { acc[i][0]=bv.x; acc[i][1]=bv.y; acc[i][2]=bv.z; acc[i][3]=bv.w; }
    } else {
        #pragma unroll
        for (int i = 0; i < 4; i++) { acc[i][0]=0; acc[i][1]=0; acc[i][2]=0; acc[i][3]=0; }
    }
    const float* wp = W + (size_t)(slice*256)*Hn + col0;
    #pragma unroll 4
    for (int k = 0; k < 256; k++) {
        float4 wv = *(const float4*)(wp + (size_t)k*Hn);
        #pragma unroll
        for (int i = 0; i < 4; i++) {
            float a = lt[rbase + i][k];
            acc[i][0] += a*wv.x; acc[i][1] += a*wv.y; acc[i][2] += a*wv.z; acc[i][3] += a*wv.w;
        }
    }
    #pragma unroll
    for (int i = 0; i < 4; i++) {
        float* op = outp + (size_t)(rt*32 + rbase + i)*Hn + col0;
        atomicAdd(op+0, acc[i][0]); atomicAdd(op+1, acc[i][1]);
        atomicAdd(op+2, acc[i][2]); atomicAdd(op+3, acc[i][3]);
    }
}

// ============ K6: f1 = sigmoid(gate)*local + (1-sig)*relu(tr) ============
__global__ __launch_bounds__(256) void k_f1ew(float* __restrict__ ws)
{
    const int i4 = blockIdx.x*256 + threadIdx.x;   // 65536 float4s
    const int row = i4 >> 7, c = (i4 & 127)*4;
    float4 lc = *(const float4*)(ws + G_OFF + (size_t)row*Hn + c);
    float4 ga = *(const float4*)(ws + GATE_OFF + (size_t)row*Hn + c);
    float4 tr = *(const float4*)(ws + TR_OFF + (size_t)row*Hn + c);
    float4 r;
    float s;
    s = 1.f/(1.f + __expf(-ga.x)); r.x = s*lc.x + (1.f-s)*fmaxf(tr.x, 0.f);
    s = 1.f/(1.f + __expf(-ga.y)); r.y = s*lc.y + (1.f-s)*fmaxf(tr.y, 0.f);
    s = 1.f/(1.f + __expf(-ga.z)); r.z = s*lc.z + (1.f-s)*fmaxf(tr.z, 0.f);
    s = 1.f/(1.f + __expf(-ga.w)); r.w = s*lc.w + (1.f-s)*fmaxf(tr.w, 0.f);
    *(float4*)(ws + F1_OFF + (size_t)row*Hn + c) = r;
}

// ============ K7: heads (reads F2 accum, applies relu) ============
__global__ __launch_bounds__(64) void k_heads(
    const float* __restrict__ W_quant, const float* __restrict__ b_quant,
    const float* __restrict__ W_ev, const float* __restrict__ b_ev,
    const float* __restrict__ ws_ro, float* __restrict__ out)
{
    const int b = blockIdx.x, lane = threadIdx.x;
    const float* fr = ws_ro + F2_OFF + (size_t)b*Hn + lane*8;
    float4 fa = *(const float4*)fr, fb = *(const float4*)(fr + 4);
    float fv[8] = {fmaxf(fa.x,0.f), fmaxf(fa.y,0.f), fmaxf(fa.z,0.f), fmaxf(fa.w,0.f),
                   fmaxf(fb.x,0.f), fmaxf(fb.y,0.f), fmaxf(fb.z,0.f), fmaxf(fb.w,0.f)};
    float acc[8];
    #pragma unroll
    for (int o = 0; o < 8; o++) acc[o] = 0.f;
    #pragma unroll
    for (int i = 0; i < 8; i++) {
        int h = lane*8 + i;
        float fh = fv[i];
        acc[0] += fh*W_quant[(0*Hn + h)*3 + 0];
        acc[1] += fh*W_quant[(0*Hn + h)*3 + 1];
        acc[2] += fh*W_quant[(0*Hn + h)*3 + 2];
        acc[3] += fh*W_quant[(1*Hn + h)*3 + 0];
        acc[4] += fh*W_quant[(1*Hn + h)*3 + 1];
        acc[5] += fh*W_quant[(1*Hn + h)*3 + 2];
        acc[6] += fh*W_ev[0*Hn + h];
        acc[7] += fh*W_ev[1*Hn + h];
    }
    #pragma unroll
    for (int o = 0; o < 8; o++) {
        #pragma unroll
        for (int s = 32; s; s >>= 1) acc[o] += __shfl_xor(acc[o], s);
    }
    if (lane == 0) {
        float q[6];
        for (int o = 0; o < 6; o++) q[o] = acc[o] + b_quant[o];
        #pragma unroll
        for (int tt = 0; tt < 2; tt++) {
            float a = q[tt*3], bb = q[tt*3+1], c = q[tt*3+2];
            float mn = fminf(a, fminf(bb, c)), mx = fmaxf(a, fmaxf(bb, c));
            float md = a + bb + c - mn - mx;
            q[tt*3] = mn; q[tt*3+1] = md; q[tt*3+2] = mx;
        }
        for (int o = 0; o < 6; o++) out[b*8 + o] = q[o];
        out[b*8 + 6] = acc[6] + b_ev[0];
        out[b*8 + 7] = acc[7] + b_ev[1];
    }
}

// ===================== Fallback: proven R4 fused kernel =====================
__device__ __forceinline__ float lds_f(const void* p, int i, int f32){
    return f32 ? ((const float*)p)[i] : __bfloat162float(((const bf16*)p)[i]);
}
__device__ __forceinline__ float2 ldpair(const void* p, int elt, int f32){
    if (f32) return ((const float2*)p)[elt >> 1];
    unsigned u = ((const unsigned*)p)[elt >> 1];
    return make_float2(lo16(u), hi16(u));
}
__device__ __forceinline__ void ld8(const void* p, int elt, int f32, float* v){
    if (f32){
        const float4* q = (const float4*)((const float*)p + elt);
        float4 a = q[0], b = q[1];
        v[0]=a.x; v[1]=a.y; v[2]=a.z; v[3]=a.w; v[4]=b.x; v[5]=b.y; v[6]=b.z; v[7]=b.w;
    } else {
        uint4 u = *(const uint4*)((const bf16*)p + elt);
        v[0]=lo16(u.x); v[1]=hi16(u.x); v[2]=lo16(u.y); v[3]=hi16(u.y);
        v[4]=lo16(u.z); v[5]=hi16(u.z); v[6]=lo16(u.w); v[7]=hi16(u.w);
    }
}
__device__ __forceinline__ void st_out(void* o, int i, int f32, float v){
    if (f32) ((float*)o)[i] = v; else ((bf16*)o)[i] = __float2bfloat16(v);
}

__global__ __launch_bounds__(256) void k_fused(
    const void* __restrict__ seq, const void* __restrict__ mask, const void* __restrict__ stat,
    const void* __restrict__ bank_keys, const void* __restrict__ bank_values,
    const int* __restrict__ cand32,
    const void* __restrict__ W_seq, const void* __restrict__ W_stat, const void* __restrict__ b_enc,
    const void* __restrict__ W_q, const void* __restrict__ b_q,
    const void* __restrict__ proto,
    const void* __restrict__ W_tr, const void* __restrict__ b_tr,
    const void* __restrict__ W_gate, const void* __restrict__ b_gate,
    const void* __restrict__ W_out, const void* __restrict__ b_out,
    const void* __restrict__ W_quant, const void* __restrict__ b_quant,
    const void* __restrict__ W_ev, const void* __restrict__ b_ev,
    void* __restrict__ out)
{
    const int b = blockIdx.x, t = threadIdx.x;
    const int w = t >> 6, lane = t & 63;
    const int h0 = 2*t, h1 = 2*t + 1;
    const int f32 = (((const unsigned short*)mask)[0] == 0) ? 1 : 0;
    const int c64 = ((cand32[1] | cand32[3] | cand32[5] | cand32[7]) == 0) ? 1 : 0;

    __shared__ __align__(16) float s_pool[16];
    __shared__ __align__(16) float s_stat[8];
    __shared__ __align__(16) float g[1536];
    __shared__ __align__(16) float s_q[Hn];
    __shared__ __align__(16) float s_sim[Cn];
    __shared__ __align__(16) float f1[Hn];
    __shared__ __align__(16) float f2[Hn];
    __shared__ float s_part[4], s_ss;
    __shared__ float s_bv[4]; __shared__ int s_bi[4];
    __shared__ float s_topv[Kn]; __shared__ int s_sel[Kn];
    __shared__ float s_w[Kn];
    __shared__ float s_score[8], s_pw[8];
    __shared__ float s_head[8][4];

    if (t < 16) {
        float acc = 0.f, ms = 0.f;
        for (int l = 0; l < 64; l++) {
            float m = lds_f(mask, b*64 + l, f32);
            ms  += m;
            acc += lds_f(seq, (b*64 + l)*16 + t, f32) * m;
        }
        s_pool[t] = acc / fmaxf(ms, 1e-6f);
    } else if (t < 24) {
        s_stat[t - 16] = lds_f(stat, b*8 + (t - 16), f32);
    }
    __syncthreads();
    {
        float a0 = lds_f(b_enc, h0, f32), a1 = lds_f(b_enc, h1, f32);
        #pragma unroll
        for (int j = 0; j < 16; j++) {
            float2 wv = ldpair(W_seq, j*Hn + h0, f32);
            a0 += s_pool[j]*wv.x; a1 += s_pool[j]*wv.y;
        }
        #pragma unroll
        for (int j = 0; j < 8; j++) {
            float2 wv = ldpair(W_stat, j*Hn + h0, f32);
            a0 += s_stat[j]*wv.x; a1 += s_stat[j]*wv.y;
        }
        a0 = fmaxf(a0, 0.f); a1 = fmaxf(a1, 0.f);
        g[h0] = a0; g[h1] = a1;
    }
    __syncthreads();
    {
        float q0 = lds_f(b_q, h0, f32), q1 = lds_f(b_q, h1, f32);
        #pragma unroll 4
        for (int j = 0; j < Hn; j++) {
            float lj = g[j];
            float2 wv = ldpair(W_q, j*Hn + h0, f32);
            q0 += lj*wv.x; q1 += lj*wv.y;
        }
        float ss = q0*q0 + q1*q1;
        #pragma unroll
        for (int o = 32; o; o >>= 1) ss += __shfl_xor(ss, o);
        if (lane == 0) s_part[w] = ss;
        __syncthreads();
        if (t == 0) s_ss = s_part[0] + s_part[1] + s_part[2] + s_part[3];
        __syncthreads();
        float inv = 1.f / fmaxf(sqrtf(s_ss), 1e-12f);
        s_q[h0] = q0*inv; s_q[h1] = q1*inv;
    }
    __syncthreads();
    float qv[8];
    #pragma unroll
    for (int i = 0; i < 8; i++) qv[i] = s_q[lane*8 + i];

    for (int c0 = w*256; c0 < w*256 + 256; c0 += 4) {
        float kf[4][8];
        #pragma unroll
        for (int u = 0; u < 4; u++) {
            int id = clamp_id(cand32[(size_t)(b*Cn + c0 + u) << c64]);
            ld8(bank_keys, id*Hn + lane*8, f32, kf[u]);
        }
        #pragma unroll
        for (int u = 0; u < 4; u++) {
            float s = 0.f;
            #pragma unroll
            for (int i = 0; i < 8; i++) s += kf[u][i]*qv[i];
            #pragma unroll
            for (int o = 32; o; o >>= 1) s += __shfl_xor(s, o);
            if (lane == 0) s_sim[c0 + u] = s;
        }
    }
    __syncthreads();
    for (int k = 0; k < Kn; k++) {
        float best = -1e30f; int bi = 0x7fffffff;
        for (int i = t; i < Cn; i += 256) {
            float v = s_sim[i];
            if (v > best || (v == best && i < bi)) { best = v; bi = i; }
        }
        #pragma unroll
        for (int o = 32; o; o >>= 1) {
            float ov = __shfl_xor(best, o); int oi = __shfl_xor(bi, o);
            if (ov > best || (ov == best && oi < bi)) { best = ov; bi = oi; }
        }
        if (lane == 0) { s_bv[w] = best; s_bi[w] = bi; }
        __syncthreads();
        if (t == 0) {
            float bv = s_bv[0]; int bbi = s_bi[0];
            for (int x = 1; x < 4; x++)
                if (s_bv[x] > bv || (s_bv[x] == bv && s_bi[x] < bbi)) { bv = s_bv[x]; bbi = s_bi[x]; }
            if (bbi < 0 || bbi >= Cn) bbi = 0;
            s_topv[k] = bv; s_sel[k] = bbi; s_sim[bbi] = -1e30f;
        }
        __syncthreads();
    }
    if (t == 0) {
        float m = s_topv[0];
        float e[Kn], ssum = 0.f;
        for (int k = 0; k < Kn; k++) { e[k] = __expf((s_topv[k] - m) * 5.0f); ssum += e[k]; }
        float inv = 1.f / ssum;
        for (int k = 0; k < Kn; k++) s_w[k] = e[k] * inv;
    }
    __syncthreads();
    {
        float a0 = 0.f, a1 = 0.f;
        #pragma unroll
        for (int k = 0; k < Kn; k++) {
            int id = clamp_id(cand32[(size_t)(b*Cn + s_sel[k]) << c64]);
            float2 v = ldpair(bank_values, id*Hn + h0, f32);
            a0 += s_w[k]*v.x; a1 += s_w[k]*v.y;
        }
        g[512 + h0] = a0; g[512 + h1] = a1;
    }
    for (int p = w; p < 8; p += 4) {
        float f[8];
        ld8(proto, p*Hn + lane*8, f32, f);
        float dq = 0.f, sq = 0.f;
        #pragma unroll
        for (int i = 0; i < 8; i++) { dq += f[i]*qv[i]; sq += f[i]*f[i]; }
        #pragma unroll
        for (int o = 32; o; o >>= 1) { dq += __shfl_xor(dq, o); sq += __shfl_xor(sq, o); }
        if (lane == 0) s_score[p] = dq / fmaxf(sqrtf(sq), 1e-12f);
    }
    __syncthreads();
    if (t == 0) {
        float m = s_score[0];
        for (int p = 1; p < 8; p++) m = fmaxf(m, s_score[p]);
        float e[8], ssum = 0.f;
        for (int p = 0; p < 8; p++) { e[p] = __expf(s_score[p] - m); ssum += e[p]; }
        float inv = 1.f / ssum;
        for (int p = 0; p < 8; p++) s_pw[p] = e[p] * inv;
    }
    __syncthreads();
    {
        float a0 = 0.f, a1 = 0.f;
        #pragma unroll
        for (int p = 0; p < 8; p++) {
            float2 v = ldpair(proto, p*Hn + h0, f32);
            a0 += s_pw[p]*v.x; a1 += s_pw[p]*v.y;
        }
        g[1024 + h0] = a0; g[1024 + h1] = a1;
    }
    __syncthreads();
    float tr0 = lds_f(b_tr, h0, f32), tr1 = lds_f(b_tr, h1, f32);
    #pragma unroll 4
    for (int j = 0; j < 1024; j++) {
        float gj = g[512 + j];
        float2 wv = ldpair(W_tr, j*Hn + h0, f32);
        tr0 += gj*wv.x; tr1 += gj*wv.y;
    }
    tr0 = fmaxf(tr0, 0.f); tr1 = fmaxf(tr1, 0.f);
    float gt0 = lds_f(b_gate, h0, f32), gt1 = lds_f(b_gate, h1, f32);
    #pragma unroll 4
    for (int j = 0; j < 1536; j++) {
        float gj = g[j];
        float2 wv = ldpair(W_gate, j*Hn + h0, f32);
        gt0 += gj*wv.x; gt1 += gj*wv.y;
    }
    gt0 = 1.f/(1.f + __expf(-gt0)); gt1 = 1.f/(1.f + __expf(-gt1));
    f1[h0] = gt0*g[h0] + (1.f - gt0)*tr0;
    f1[h1] = gt1*g[h1] + (1.f - gt1)*tr1;
    __syncthreads();
    {
        float o0 = lds_f(b_out, h0, f32), o1 = lds_f(b_out, h1, f32);
        #pragma unroll 4
        for (int j = 0; j < Hn; j++) {
            float fj = f1[j];
            float2 wv = ldpair(W_out, j*Hn + h0, f32);
            o0 += fj*wv.x; o1 += fj*wv.y;
        }
        o0 = fmaxf(o0, 0.f); o1 = fmaxf(o1, 0.f);
        f2[h0] = o0; f2[h1] = o1;
    }
    __syncthreads();
    {
        float acc[8];
        #pragma unroll
        for (int o = 0; o < 8; o++) acc[o] = 0.f;
        for (int h = t; h < Hn; h += 256) {
            float fh = f2[h];
            acc[0] += fh*lds_f(W_quant, (0*Hn + h)*3 + 0, f32);
            acc[1] += fh*lds_f(W_quant, (0*Hn + h)*3 + 1, f32);
            acc[2] += fh*lds_f(W_quant, (0*Hn + h)*3 + 2, f32);
            acc[3] += fh*lds_f(W_quant, (1*Hn + h)*3 + 0, f32);
            acc[4] += fh*lds_f(W_quant, (1*Hn + h)*3 + 1, f32);
            acc[5] += fh*lds_f(W_quant, (1*Hn + h)*3 + 2, f32);
            acc[6] += fh*lds_f(W_ev, 0*Hn + h, f32);
            acc[7] += fh*lds_f(W_ev, 1*Hn + h, f32);
        }
        #pragma unroll
        for (int o = 0; o < 8; o++) {
            float v = acc[o];
            #pragma unroll
            for (int s = 32; s; s >>= 1) v += __shfl_xor(v, s);
            if (lane == 0) s_head[o][w] = v;
        }
        __syncthreads();
        if (t == 0) {
            float q[6];
            for (int o = 0; o < 6; o++)
                q[o] = s_head[o][0] + s_head[o][1] + s_head[o][2] + s_head[o][3] + lds_f(b_quant, o, f32);
            #pragma unroll
            for (int tt = 0; tt < 2; tt++) {
                float a = q[tt*3], bb = q[tt*3+1], c = q[tt*3+2];
                float mn = fminf(a, fminf(bb, c)), mx = fmaxf(a, fmaxf(bb, c));
                float md = a + bb + c - mn - mx;
                q[tt*3] = mn; q[tt*3+1] = md; q[tt*3+2] = mx;
            }
            for (int o = 0; o < 6; o++) st_out(out, b*8 + o, f32, q[o]);
            float l0 = s_head[6][0] + s_head[6][1] + s_head[6][2] + s_head[6][3] + lds_f(b_ev, 0, f32);
            float l1 = s_head[7][0] + s_head[7][1] + s_head[7][2] + s_head[7][3] + lds_f(b_ev, 1, f32);
            st_out(out, b*8 + 6, f32, l0);
            st_out(out, b*8 + 7, f32, l1);
        }
    }
}

extern "C" void kernel_launch(void* const* d_in, const int* in_sizes, int n_in,
                              void* d_out, int out_size, void* d_ws, size_t ws_size,
                              hipStream_t stream) {
    static const int expect[22] = {
        512*64*16, 512*64, 512*8, 50000*512, 50000*512, 512*1024,
        16*512, 8*512, 512, 512*512, 512, 8*512,
        1024*512, 512, 1536*512, 512, 512*512, 512,
        2*512*3, 2*3, 2*512, 2
    };
    if (n_in != 22 || out_size != 512*8) return;
    for (int i = 0; i < 22; i++) if (in_sizes[i] != expect[i]) return;

    if (ws_size < (size_t)WS_FLOATS * 4) {
        k_fused<<<Bn, 256, 0, stream>>>(
            d_in[0], d_in[1], d_in[2], d_in[3], d_in[4], (const int*)d_in[5],
            d_in[6], d_in[7], d_in[8], d_in[9], d_in[10], d_in[11],
            d_in[12], d_in[13], d_in[14], d_in[15], d_in[16], d_in[17],
            d_in[18], d_in[19], d_in[20], d_in[21], d_out);
        return;
    }

    float* ws = (float*)d_ws;
    int* iws = (int*)(ws + GATE_OFF);
    int* hist   = iws + HIST_I;
    int* cursor = iws + CURSOR_I;
    int* offs   = iws + OFFS_I;
    int* chpref = iws + CHPREF_I;
    unsigned* refs = (unsigned*)(ws + DONOR_OFF);   // 524288 u32 = DONOR+PROTO slabs (dead until k_select)

    // zero accumulation / index targets (capture-legal async memsets)
    hipMemsetAsync(ws + QRAW_OFF, 0, (size_t)512*512*4, stream);
    hipMemsetAsync(hist, 0, (size_t)2*NIDPAD*4, stream);          // hist + cursor
    hipMemsetAsync(ws + TR_OFF, 0, (size_t)512*512*4, stream);

    k_enc<<<Bn, 256, 0, stream>>>((const float*)d_in[0], (const float*)d_in[1],
                                  (const float*)d_in[2], (const float*)d_in[6],
                                  (const float*)d_in[7], (const float*)d_in[8],
                                  (const int*)d_in[5], ws);
    k_scanA<<<NIDPAD/256, 256, 0, stream>>>(hist, offs, chpref);
    k_scanB<<<1, 256, 0, stream>>>(chpref);
    k_scatter<<<(Bn*Cn)/256, 256, 0, stream>>>((const int*)d_in[5], cursor, offs, chpref, refs);
    k_qgemm_sk<<<dim3(8, 8, 4), 256, 0, stream>>>(
        (const float*)d_in[9], (const float*)d_in[10], ws + G_OFF, 512, 0, ws + QRAW_OFF);
    k_qnorm<<<Bn, 64, 0, stream>>>(ws);
    k_dotinv<<<NBANK/4, 256, 0, stream>>>((const float*)d_in[3], refs, offs, chpref, ws);
    k_select<<<Bn, 256, 0, stream>>>((const float*)d_in[4], (const int*)d_in[5],
                                     (const float*)d_in[11], ws);
    // index arrays and SIM are dead after k_select; re-zero for atomic accumulation
    hipMemsetAsync(ws + GATE_OFF, 0, (size_t)512*512*4, stream);
    hipMemsetAsync(ws + F2_OFF, 0, (size_t)512*512*4, stream);
    k_gatetr_sk<<<dim3(4, 16, 10), 256, 0, stream>>>(
        (const float*)d_in[12], (const float*)d_in[13],
        (const float*)d_in[14], (const float*)d_in[15], ws);
    k_f1ew<<<256, 256, 0, stream>>>(ws);
    k_qgemm_sk<<<dim3(8, 8, 4), 256, 0, stream>>>(
        (const float*)d_in[16], (const float*)d_in[17], ws + F1_OFF, 512, 0, ws + F2_OFF);
    k_heads<<<Bn, 64, 0, stream>>>((const float*)d_in[18], (const float*)d_in[19],
                                   (const float*)d_in[20], (const float*)d_in[21],
                                   ws, (float*)d_out);
}

// Round 2
// 508.055 us; speedup vs baseline: 1.0762x; 1.0762x over previous
//
#include <hip/hip_runtime.h>
#include <hip/hip_bf16.h>

typedef __hip_bfloat16 bf16;

__device__ __forceinline__ float lo16(unsigned u){ return __uint_as_float(u << 16); }
__device__ __forceinline__ float hi16(unsigned u){ return __uint_as_float(u & 0xffff0000u); }

// B=512, L=64, DDYN=16, DSTAT=8, H=512, C=1024, K=16, P=8, T=2, Q=3
#define Bn 512
#define Hn 512
#define Cn 1024
#define Kn 16
#define NBANK 50000
#define NIDPAD 50176   // 196*256

__device__ __forceinline__ int clamp_id(int id){
    return (id < 0) ? 0 : ((id >= NBANK) ? (NBANK - 1) : id);
}

// ---------------- ws layout (floats), 8 MB total ----------------
// A    @0        : qGEMM partial0 -> QRAW(normed) -> gate partial0 -> F1
// B    @262144   : LOCAL
// C    @524288   : refs.lo -> DONOR
// D    @786432   : refs.hi -> PROTO
// E.lo @1048576  : qGEMM partial1 -> SIM.lo -> gate partial1 -> f2 partial0
// E.hi @1310720  : qGEMM partial2 -> SIM.hi -> gate partial2 -> f2 partial1
// F    @1572864  : ints(hist/cursor/gtot/offs) -> tr partial0 -> f2 partial2
// G    @1835008  : qGEMM partial3 -> tr partial1 -> f2 partial3
#define A_OFF    0
#define B_OFF    262144
#define C_OFF    524288
#define D_OFF    786432
#define SIM_OFF  1048576
#define ELO_OFF  1048576
#define EHI_OFF  1310720
#define F_OFF    1572864
#define G_OFF2   1835008
#define WS_FLOATS 2097152

// int offsets within F region (as int*)
#define HIST_I   0
#define CURSOR_I NIDPAD
#define GTOT_I   (2*NIDPAD)
#define OFFS_I   (2*NIDPAD + 256)   // total ints used: 3*NIDPAD+256 < 262144

// ============ K1: encoder -> LOCAL slab; fused candidate histogram ============
__global__ __launch_bounds__(256) void k_enc(
    const float* __restrict__ seq, const float* __restrict__ mask, const float* __restrict__ stat,
    const float* __restrict__ W_seq, const float* __restrict__ W_stat, const float* __restrict__ b_enc,
    const int* __restrict__ cand32, float* __restrict__ ws)
{
    const int b = blockIdx.x, t = threadIdx.x;
    const int h0 = 2*t, h1 = 2*t + 1;

    {   // histogram of this row's 1024 candidate ids
        const int c64 = ((cand32[1] | cand32[3] | cand32[5] | cand32[7]) == 0) ? 1 : 0;
        int* hist = (int*)(ws + F_OFF) + HIST_I;
        #pragma unroll
        for (int u = 0; u < 4; u++) {
            int idx = b*Cn + u*256 + t;
            atomicAdd(&hist[clamp_id(cand32[(size_t)idx << c64])], 1);
        }
    }

    __shared__ float s_pool[16], s_stat[8];
    if (t < 16) {
        float acc = 0.f, ms = 0.f;
        for (int l = 0; l < 64; l++) {
            float m = mask[b*64 + l];
            ms  += m;
            acc += seq[(b*64 + l)*16 + t] * m;
        }
        s_pool[t] = acc / fmaxf(ms, 1e-6f);
    } else if (t < 24) {
        s_stat[t - 16] = stat[b*8 + (t - 16)];
    }
    __syncthreads();
    float a0 = b_enc[h0], a1 = b_enc[h1];
    #pragma unroll
    for (int j = 0; j < 16; j++) {
        float2 wv = *(const float2*)(W_seq + j*Hn + h0);
        a0 += s_pool[j]*wv.x; a1 += s_pool[j]*wv.y;
    }
    #pragma unroll
    for (int j = 0; j < 8; j++) {
        float2 wv = *(const float2*)(W_stat + j*Hn + h0);
        a0 += s_stat[j]*wv.x; a1 += s_stat[j]*wv.y;
    }
    float* g = ws + B_OFF + (size_t)b*Hn;
    g[h0] = fmaxf(a0, 0.f); g[h1] = fmaxf(a1, 0.f);
}

// ============ K2: fused scan — per-chunk exclusive scan + atomic chunk base ============
__global__ __launch_bounds__(256) void k_scan(
    const int* __restrict__ hist, int* __restrict__ offs, int* __restrict__ gtot)
{
    __shared__ int s[256]; __shared__ int sbase;
    const int t = threadIdx.x, g = blockIdx.x*256 + t;
    const int v = hist[g];
    s[t] = v; __syncthreads();
    #pragma unroll
    for (int off = 1; off < 256; off <<= 1) {
        int x = (t >= off) ? s[t - off] : 0;
        __syncthreads();
        s[t] += x;
        __syncthreads();
    }
    if (t == 255) sbase = atomicAdd(gtot, s[255]);
    __syncthreads();
    offs[g] = sbase + s[t] - v;   // absolute exclusive offset (chunk order arbitrary)
}

// ============ K3: scatter (b,c) refs into id buckets ============
__global__ __launch_bounds__(256) void k_scatter(
    const int* __restrict__ cand32, int* __restrict__ cursor,
    const int* __restrict__ offs, unsigned* __restrict__ refs)
{
    const int i = blockIdx.x*256 + threadIdx.x;   // i = b*1024 + c
    const int c64 = ((cand32[1] | cand32[3] | cand32[5] | cand32[7]) == 0) ? 1 : 0;
    const int id = clamp_id(cand32[(size_t)i << c64]);
    const int pos = atomicAdd(&cursor[id], 1);
    refs[offs[id] + pos] = (unsigned)i;
}

// ============ K4: GEMM 512x512x512, split-K to 4 partial buffers (no atomics) ============
// grid (8 ct, 8 rt, 4 kz); tile 64r x 64c, K-slice 128; thread 4r x 4c
__global__ __launch_bounds__(256) void k_qgemm_p(
    const float* __restrict__ W, const float* __restrict__ bias,
    const float* __restrict__ in,
    float* __restrict__ P0, float* __restrict__ P1,
    float* __restrict__ P2, float* __restrict__ P3)
{
    const int ct = blockIdx.x, rt = blockIdx.y, kz = blockIdx.z, t = threadIdx.x;
    __shared__ float lt[64][132];
    {   // stage 64 rows x 128 k
        int r = t >> 2, c0 = (t & 3)*32;
        const float* src = in + (size_t)(rt*64 + r)*Hn + kz*128 + c0;
        #pragma unroll
        for (int i = 0; i < 8; i++)
            *(float4*)&lt[r][c0 + i*4] = *(const float4*)(src + i*4);
    }
    __syncthreads();
    const int col0 = ct*64 + (t & 15)*4, rbase = (t >> 4)*4;
    float acc[4][4];
    if (kz == 0) {
        float4 bv = *(const float4*)(bias + col0);
        #pragma unroll
        for (int i = 0; i < 4; i++) { acc[i][0]=bv.x; acc[i][1]=bv.y; acc[i][2]=bv.z; acc[i][3]=bv.w; }
    } else {
        #pragma unroll
        for (int i = 0; i < 4; i++) { acc[i][0]=0; acc[i][1]=0; acc[i][2]=0; acc[i][3]=0; }
    }
    const float* wp = W + (size_t)(kz*128)*Hn + col0;
    #pragma unroll 4
    for (int k = 0; k < 128; k++) {
        float4 wv = *(const float4*)(wp + (size_t)k*Hn);
        #pragma unroll
        for (int i = 0; i < 4; i++) {
            float a = lt[rbase + i][k];
            acc[i][0] += a*wv.x; acc[i][1] += a*wv.y; acc[i][2] += a*wv.z; acc[i][3] += a*wv.w;
        }
    }
    float* outp = (kz == 0) ? P0 : (kz == 1) ? P1 : (kz == 2) ? P2 : P3;
    #pragma unroll
    for (int i = 0; i < 4; i++) {
        float* op = outp + (size_t)(rt*64 + rbase + i)*Hn + col0;
        *(float4*)op = make_float4(acc[i][0], acc[i][1], acc[i][2], acc[i][3]);
    }
}

// ============ K5: sum 4 q-partials + normalize -> QRAW (A) ============
__global__ __launch_bounds__(256) void k_qnorm(float* __restrict__ ws)
{
    const int b = blockIdx.x*4 + (threadIdx.x >> 6), lane = threadIdx.x & 63;
    const size_t o = (size_t)b*Hn + lane*8;
    const float* p0 = ws + A_OFF   + o;
    const float* p1 = ws + ELO_OFF + o;
    const float* p2 = ws + EHI_OFF + o;
    const float* p3 = ws + G_OFF2  + o;
    float4 qa, qb;
    {
        float4 a0 = *(const float4*)p0, a1 = *(const float4*)p1,
               a2 = *(const float4*)p2, a3 = *(const float4*)p3;
        qa = make_float4(((a0.x+a1.x)+a2.x)+a3.x, ((a0.y+a1.y)+a2.y)+a3.y,
                         ((a0.z+a1.z)+a2.z)+a3.z, ((a0.w+a1.w)+a2.w)+a3.w);
        float4 b0 = *(const float4*)(p0+4), b1 = *(const float4*)(p1+4),
               b2 = *(const float4*)(p2+4), b3 = *(const float4*)(p3+4);
        qb = make_float4(((b0.x+b1.x)+b2.x)+b3.x, ((b0.y+b1.y)+b2.y)+b3.y,
                         ((b0.z+b1.z)+b2.z)+b3.z, ((b0.w+b1.w)+b2.w)+b3.w);
    }
    float ss = qa.x*qa.x + qa.y*qa.y + qa.z*qa.z + qa.w*qa.w
             + qb.x*qb.x + qb.y*qb.y + qb.z*qb.z + qb.w*qb.w;
    #pragma unroll
    for (int o2 = 32; o2; o2 >>= 1) ss += __shfl_xor(ss, o2);
    float inv = 1.f / fmaxf(sqrtf(ss), 1e-12f);
    qa.x *= inv; qa.y *= inv; qa.z *= inv; qa.w *= inv;
    qb.x *= inv; qb.y *= inv; qb.z *= inv; qb.w *= inv;
    float* qr = ws + A_OFF + o;
    *(float4*)qr = qa; *(float4*)(qr + 4) = qb;
}

// ============ K6: inverted-index sim — pipelined, refs in-register ============
#define DI_LOAD(R0,R1,R2,R3,A0,Bq0,A1,Bq1,A2,Bq2,A3,Bq3,BASE) do {                       \
    int m_ = n - 1;                                                                      \
    int j0_=(BASE), j1_=(BASE)+1, j2_=(BASE)+2, j3_=(BASE)+3;                            \
    j0_ = j0_>m_?m_:j0_; j1_ = j1_>m_?m_:j1_; j2_ = j2_>m_?m_:j2_; j3_ = j3_>m_?m_:j3_;  \
    R0 = (j0_<64)?(unsigned)__shfl((int)refv,j0_):refs[start+j0_];                       \
    R1 = (j1_<64)?(unsigned)__shfl((int)refv,j1_):refs[start+j1_];                       \
    R2 = (j2_<64)?(unsigned)__shfl((int)refv,j2_):refs[start+j2_];                       \
    R3 = (j3_<64)?(unsigned)__shfl((int)refv,j3_):refs[start+j3_];                       \
    const float* q0_ = qbase + (size_t)(R0>>10)*Hn + lane*8;                             \
    const float* q1_ = qbase + (size_t)(R1>>10)*Hn + lane*8;                             \
    const float* q2_ = qbase + (size_t)(R2>>10)*Hn + lane*8;                             \
    const float* q3_ = qbase + (size_t)(R3>>10)*Hn + lane*8;                             \
    A0 = *(const float4*)q0_; Bq0 = *(const float4*)(q0_+4);                             \
    A1 = *(const float4*)q1_; Bq1 = *(const float4*)(q1_+4);                             \
    A2 = *(const float4*)q2_; Bq2 = *(const float4*)(q2_+4);                             \
    A3 = *(const float4*)q3_; Bq3 = *(const float4*)(q3_+4);                             \
} while(0)

#define DI_COMP(R0,R1,R2,R3,A0,Bq0,A1,Bq1,A2,Bq2,A3,Bq3,BASE) do {                       \
    float s0_ = ka.x*A0.x + ka.y*A0.y + ka.z*A0.z + ka.w*A0.w                            \
              + kb.x*Bq0.x + kb.y*Bq0.y + kb.z*Bq0.z + kb.w*Bq0.w;                       \
    float s1_ = ka.x*A1.x + ka.y*A1.y + ka.z*A1.z + ka.w*A1.w                            \
              + kb.x*Bq1.x + kb.y*Bq1.y + kb.z*Bq1.z + kb.w*Bq1.w;                       \
    float s2_ = ka.x*A2.x + ka.y*A2.y + ka.z*A2.z + ka.w*A2.w                            \
              + kb.x*Bq2.x + kb.y*Bq2.y + kb.z*Bq2.z + kb.w*Bq2.w;                       \
    float s3_ = ka.x*A3.x + ka.y*A3.y + ka.z*A3.z + ka.w*A3.w                            \
              + kb.x*Bq3.x + kb.y*Bq3.y + kb.z*Bq3.z + kb.w*Bq3.w;                       \
    s0_ += __shfl_xor(s0_,32); s1_ += __shfl_xor(s1_,32);                                \
    s2_ += __shfl_xor(s2_,32); s3_ += __shfl_xor(s3_,32);                                \
    s0_ += __shfl_xor(s0_,16); s1_ += __shfl_xor(s1_,16);                                \
    s2_ += __shfl_xor(s2_,16); s3_ += __shfl_xor(s3_,16);                                \
    s0_ += __shfl_xor(s0_, 8); s1_ += __shfl_xor(s1_, 8);                                \
    s2_ += __shfl_xor(s2_, 8); s3_ += __shfl_xor(s3_, 8);                                \
    int d_ = (lane >> 3) & 3;                                                            \
    float t_ = d_==0 ? s0_ : d_==1 ? s1_ : d_==2 ? s2_ : s3_;                            \
    t_ += __shfl_xor(t_, 4); t_ += __shfl_xor(t_, 2); t_ += __shfl_xor(t_, 1);           \
    if ((lane & 7) == 0 && lane < 32) {                                                  \
        int dd_ = lane >> 3;                                                             \
        if ((BASE) + dd_ < n) {                                                          \
            unsigned rs_ = dd_==0 ? R0 : dd_==1 ? R1 : dd_==2 ? R2 : R3;                 \
            simw[rs_] = t_;                                                              \
        }                                                                                \
    }                                                                                    \
} while(0)

__global__ __launch_bounds__(256, 4) void k_dotinv(
    const float* __restrict__ bank_keys, const unsigned* __restrict__ refs,
    const int* __restrict__ offs, const int* __restrict__ cnt,
    float* __restrict__ ws)
{
    const int id = blockIdx.x*4 + (threadIdx.x >> 6);
    const int lane = threadIdx.x & 63;
    const int n = cnt[id];
    if (n <= 0) return;
    const int start = offs[id];

    const float* kp = bank_keys + (size_t)id*Hn + lane*8;
    float4 ka = *(const float4*)kp, kb = *(const float4*)(kp + 4);
    const unsigned refv = refs[start + (lane < n ? lane : n - 1)];
    const float* qbase = ws + A_OFF;
    float* simw = ws + SIM_OFF;

    unsigned Ar0,Ar1,Ar2,Ar3, Br0=0,Br1=0,Br2=0,Br3=0;
    float4 Aa0,Ab0,Aa1,Ab1,Aa2,Ab2,Aa3,Ab3;
    float4 Ba0,Bb0,Ba1,Bb1,Ba2,Bb2,Ba3,Bb3;
    Ba0=Bb0=Ba1=Bb1=Ba2=Bb2=Ba3=Bb3=make_float4(0.f,0.f,0.f,0.f);

    DI_LOAD(Ar0,Ar1,Ar2,Ar3, Aa0,Ab0,Aa1,Ab1,Aa2,Ab2,Aa3,Ab3, 0);
    for (int base = 0; ; ) {
        if (base + 4 < n) DI_LOAD(Br0,Br1,Br2,Br3, Ba0,Bb0,Ba1,Bb1,Ba2,Bb2,Ba3,Bb3, base + 4);
        DI_COMP(Ar0,Ar1,Ar2,Ar3, Aa0,Ab0,Aa1,Ab1,Aa2,Ab2,Aa3,Ab3, base);
        if (base + 8 < n) DI_LOAD(Ar0,Ar1,Ar2,Ar3, Aa0,Ab0,Aa1,Ab1,Aa2,Ab2,Aa3,Ab3, base + 8);
        DI_COMP(Br0,Br1,Br2,Br3, Ba0,Bb0,Ba1,Bb1,Ba2,Bb2,Ba3,Bb3, base + 4);
        base += 8;
        if (base >= n) break;
    }
}

// ============ K7: top-16 + softmax + donor + proto ============
__global__ __launch_bounds__(256) void k_select(
    const float* __restrict__ bank_values, const int* __restrict__ cand32,
    const float* __restrict__ proto, float* __restrict__ ws)
{
    const int b = blockIdx.x, t = threadIdx.x;
    const int w = t >> 6, lane = t & 63;
    const int h0 = 2*t, h1 = 2*t + 1;
    const int c64 = ((cand32[1] | cand32[3] | cand32[5] | cand32[7]) == 0) ? 1 : 0;

    __shared__ __align__(16) float s_sim[Cn];
    __shared__ float s_bv[4]; __shared__ int s_bi[4];
    __shared__ float s_topv[Kn]; __shared__ int s_sel[Kn];
    __shared__ float s_w[Kn];
    __shared__ float s_score[8], s_pw[8];

    *(float4*)&s_sim[t*4] = *(const float4*)(ws + SIM_OFF + (size_t)b*Cn + t*4);

    const float* qr = ws + A_OFF + (size_t)b*Hn + lane*8;
    float4 qa = *(const float4*)qr, qb = *(const float4*)(qr + 4);
    float qv[8] = {qa.x, qa.y, qa.z, qa.w, qb.x, qb.y, qb.z, qb.w};
    __syncthreads();

    for (int k = 0; k < Kn; k++) {
        float best = -1e30f; int bi = 0x7fffffff;
        for (int i = t; i < Cn; i += 256) {
            float v = s_sim[i];
            if (v > best || (v == best && i < bi)) { best = v; bi = i; }
        }
        #pragma unroll
        for (int o = 32; o; o >>= 1) {
            float ov = __shfl_xor(best, o); int oi = __shfl_xor(bi, o);
            if (ov > best || (ov == best && oi < bi)) { best = ov; bi = oi; }
        }
        if (lane == 0) { s_bv[w] = best; s_bi[w] = bi; }
        __syncthreads();
        if (t == 0) {
            float bv = s_bv[0]; int bbi = s_bi[0];
            for (int x = 1; x < 4; x++)
                if (s_bv[x] > bv || (s_bv[x] == bv && s_bi[x] < bbi)) { bv = s_bv[x]; bbi = s_bi[x]; }
            if (bbi < 0 || bbi >= Cn) bbi = 0;
            s_topv[k] = bv; s_sel[k] = bbi; s_sim[bbi] = -1e30f;
        }
        __syncthreads();
    }

    if (t == 0) {
        float m = s_topv[0];
        float e[Kn], ssum = 0.f;
        for (int k = 0; k < Kn; k++) { e[k] = __expf((s_topv[k] - m) * 5.0f); ssum += e[k]; }
        float inv = 1.f / ssum;
        for (int k = 0; k < Kn; k++) s_w[k] = e[k] * inv;
    }
    for (int p = w; p < 8; p += 4) {
        const float* pp = proto + (size_t)p*Hn + lane*8;
        float4 pa = *(const float4*)pp, pb = *(const float4*)(pp + 4);
        float f[8] = {pa.x, pa.y, pa.z, pa.w, pb.x, pb.y, pb.z, pb.w};
        float dq = 0.f, sq = 0.f;
        #pragma unroll
        for (int i = 0; i < 8; i++) { dq += f[i]*qv[i]; sq += f[i]*f[i]; }
        #pragma unroll
        for (int o = 32; o; o >>= 1) { dq += __shfl_xor(dq, o); sq += __shfl_xor(sq, o); }
        if (lane == 0) s_score[p] = dq / fmaxf(sqrtf(sq), 1e-12f);
    }
    __syncthreads();
    if (t == 0) {
        float m = s_score[0];
        for (int p = 1; p < 8; p++) m = fmaxf(m, s_score[p]);
        float e[8], ssum = 0.f;
        for (int p = 0; p < 8; p++) { e[p] = __expf(s_score[p] - m); ssum += e[p]; }
        float inv = 1.f / ssum;
        for (int p = 0; p < 8; p++) s_pw[p] = e[p] * inv;
    }
    __syncthreads();

    {
        float a0 = 0.f, a1 = 0.f;
        #pragma unroll
        for (int k = 0; k < Kn; k++) {
            int id = clamp_id(cand32[(size_t)(b*Cn + s_sel[k]) << c64]);
            float2 v = *(const float2*)(bank_values + (size_t)id*Hn + h0);
            a0 += s_w[k]*v.x; a1 += s_w[k]*v.y;
        }
        float* gd = ws + C_OFF + (size_t)b*Hn;
        gd[h0] = a0; gd[h1] = a1;
    }
    {
        float a0 = 0.f, a1 = 0.f;
        #pragma unroll
        for (int p = 0; p < 8; p++) {
            float2 v = *(const float2*)(proto + (size_t)p*Hn + h0);
            a0 += s_pw[p]*v.x; a1 += s_pw[p]*v.y;
        }
        float* gp = ws + D_OFF + (size_t)b*Hn;
        gp[h0] = a0; gp[h1] = a1;
    }
}

// ============ K8: gate/tr -> 5 partial buffers (no atomics) ============
// grid (4 ct, 16 rt, 5 z): z<3 gate K-slice z (K=512 = slab z); z>=3 tr slice z-3
// tile 32r x 128c; thread 4r x 4c; K staged in two 256-halves
__global__ __launch_bounds__(256) void k_gatetr_p(
    const float* __restrict__ W_tr, const float* __restrict__ b_tr,
    const float* __restrict__ W_gate, const float* __restrict__ b_gate,
    float* __restrict__ ws)
{
    const int ct = blockIdx.x, rt = blockIdx.y, z = blockIdx.z, t = threadIdx.x;
    const int isGate = (z < 3);
    const int sl = isGate ? z : (z - 3);
    const float* W = isGate ? (W_gate + (size_t)(z*512)*Hn) : (W_tr + (size_t)(sl*512)*Hn);
    const float* slab = ws + B_OFF + (size_t)(isGate ? z : (sl + 1))*262144;
    float* outp = isGate
        ? ((z == 0) ? ws + A_OFF : (z == 1) ? ws + ELO_OFF : ws + EHI_OFF)
        : ((sl == 0) ? ws + F_OFF : ws + G_OFF2);

    __shared__ float lt[32][260];
    const int col0 = ct*128 + (t & 31)*4, rbase = (t >> 5)*4;
    float acc[4][4];
    if (z == 0 || z == 3) {
        const float* bias = isGate ? b_gate : b_tr;
        float4 bv = *(const float4*)(bias + col0);
        #pragma unroll
        for (int i = 0; i < 4; i++) { acc[i][0]=bv.x; acc[i][1]=bv.y; acc[i][2]=bv.z; acc[i][3]=bv.w; }
    } else {
        #pragma unroll
        for (int i = 0; i < 4; i++) { acc[i][0]=0; acc[i][1]=0; acc[i][2]=0; acc[i][3]=0; }
    }

    #pragma unroll
    for (int h = 0; h < 2; h++) {
        if (h) __syncthreads();
        {   // stage 32 rows x 256 k
            int r = t >> 3, c0 = (t & 7)*32;
            const float* src = slab + (size_t)(rt*32 + r)*Hn + h*256 + c0;
            #pragma unroll
            for (int i = 0; i < 8; i++)
                *(float4*)&lt[r][c0 + i*4] = *(const float4*)(src + i*4);
        }
        __syncthreads();
        const float* wp = W + (size_t)(h*256)*Hn + col0;
        #pragma unroll 4
        for (int k = 0; k < 256; k++) {
            float4 wv = *(const float4*)(wp + (size_t)k*Hn);
            #pragma unroll
            for (int i = 0; i < 4; i++) {
                float a = lt[rbase + i][k];
                acc[i][0] += a*wv.x; acc[i][1] += a*wv.y; acc[i][2] += a*wv.z; acc[i][3] += a*wv.w;
            }
        }
    }
    #pragma unroll
    for (int i = 0; i < 4; i++) {
        float* op = outp + (size_t)(rt*32 + rbase + i)*Hn + col0;
        *(float4*)op = make_float4(acc[i][0], acc[i][1], acc[i][2], acc[i][3]);
    }
}

// ============ K9: f1 = sigmoid(Σgate)*local + (1-sig)*relu(Σtr) -> A ============
__global__ __launch_bounds__(256) void k_f1ew(float* __restrict__ ws)
{
    const int i4 = blockIdx.x*256 + threadIdx.x;   // 65536 float4s
    const size_t off = (size_t)(i4 >> 7)*Hn + (i4 & 127)*4;
    float4 lc = *(const float4*)(ws + B_OFF + off);
    float4 g0 = *(const float4*)(ws + A_OFF + off);
    float4 g1 = *(const float4*)(ws + ELO_OFF + off);
    float4 g2 = *(const float4*)(ws + EHI_OFF + off);
    float4 t0 = *(const float4*)(ws + F_OFF + off);
    float4 t1 = *(const float4*)(ws + G_OFF2 + off);
    float4 ga = make_float4((g0.x+g1.x)+g2.x, (g0.y+g1.y)+g2.y,
                            (g0.z+g1.z)+g2.z, (g0.w+g1.w)+g2.w);
    float4 tr = make_float4(t0.x+t1.x, t0.y+t1.y, t0.z+t1.z, t0.w+t1.w);
    float4 r;
    float s;
    s = 1.f/(1.f + __expf(-ga.x)); r.x = s*lc.x + (1.f-s)*fmaxf(tr.x, 0.f);
    s = 1.f/(1.f + __expf(-ga.y)); r.y = s*lc.y + (1.f-s)*fmaxf(tr.y, 0.f);
    s = 1.f/(1.f + __expf(-ga.z)); r.z = s*lc.z + (1.f-s)*fmaxf(tr.z, 0.f);
    s = 1.f/(1.f + __expf(-ga.w)); r.w = s*lc.w + (1.f-s)*fmaxf(tr.w, 0.f);
    *(float4*)(ws + A_OFF + off) = r;
}

// ============ K10: heads (sums 4 f2-partials, relu, project) ============
__global__ __launch_bounds__(64) void k_heads(
    const float* __restrict__ W_quant, const float* __restrict__ b_quant,
    const float* __restrict__ W_ev, const float* __restrict__ b_ev,
    const float* __restrict__ ws_ro, float* __restrict__ out)
{
    const int b = blockIdx.x, lane = threadIdx.x;
    const size_t o = (size_t)b*Hn + lane*8;
    const float* p0 = ws_ro + ELO_OFF + o;
    const float* p1 = ws_ro + EHI_OFF + o;
    const float* p2 = ws_ro + F_OFF + o;
    const float* p3 = ws_ro + G_OFF2 + o;
    float4 a0 = *(const float4*)p0, a1 = *(const float4*)p1,
           a2 = *(const float4*)p2, a3 = *(const float4*)p3;
    float4 b0 = *(const float4*)(p0+4), b1 = *(const float4*)(p1+4),
           b2 = *(const float4*)(p2+4), b3 = *(const float4*)(p3+4);
    float fv[8] = {
        fmaxf(((a0.x+a1.x)+a2.x)+a3.x, 0.f), fmaxf(((a0.y+a1.y)+a2.y)+a3.y, 0.f),
        fmaxf(((a0.z+a1.z)+a2.z)+a3.z, 0.f), fmaxf(((a0.w+a1.w)+a2.w)+a3.w, 0.f),
        fmaxf(((b0.x+b1.x)+b2.x)+b3.x, 0.f), fmaxf(((b0.y+b1.y)+b2.y)+b3.y, 0.f),
        fmaxf(((b0.z+b1.z)+b2.z)+b3.z, 0.f), fmaxf(((b0.w+b1.w)+b2.w)+b3.w, 0.f)};
    float acc[8];
    #pragma unroll
    for (int q = 0; q < 8; q++) acc[q] = 0.f;
    #pragma unroll
    for (int i = 0; i < 8; i++) {
        int h = lane*8 + i;
        float fh = fv[i];
        acc[0] += fh*W_quant[(0*Hn + h)*3 + 0];
        acc[1] += fh*W_quant[(0*Hn + h)*3 + 1];
        acc[2] += fh*W_quant[(0*Hn + h)*3 + 2];
        acc[3] += fh*W_quant[(1*Hn + h)*3 + 0];
        acc[4] += fh*W_quant[(1*Hn + h)*3 + 1];
        acc[5] += fh*W_quant[(1*Hn + h)*3 + 2];
        acc[6] += fh*W_ev[0*Hn + h];
        acc[7] += fh*W_ev[1*Hn + h];
    }
    #pragma unroll
    for (int q = 0; q < 8; q++) {
        #pragma unroll
        for (int s = 32; s; s >>= 1) acc[q] += __shfl_xor(acc[q], s);
    }
    if (lane == 0) {
        float qv[6];
        for (int q = 0; q < 6; q++) qv[q] = acc[q] + b_quant[q];
        #pragma unroll
        for (int tt = 0; tt < 2; tt++) {
            float a = qv[tt*3], bb = qv[tt*3+1], c = qv[tt*3+2];
            float mn = fminf(a, fminf(bb, c)), mx = fmaxf(a, fmaxf(bb, c));
            float md = a + bb + c - mn - mx;
            qv[tt*3] = mn; qv[tt*3+1] = md; qv[tt*3+2] = mx;
        }
        for (int q = 0; q < 6; q++) out[b*8 + q] = qv[q];
        out[b*8 + 6] = acc[6] + b_ev[0];
        out[b*8 + 7] = acc[7] + b_ev[1];
    }
}

// ===================== Fallback: proven R4 fused kernel =====================
__device__ __forceinline__ float lds_f(const void* p, int i, int f32){
    return f32 ? ((const float*)p)[i] : __bfloat162float(((const bf16*)p)[i]);
}
__device__ __forceinline__ float2 ldpair(const void* p, int elt, int f32){
    if (f32) return ((const float2*)p)[elt >> 1];
    unsigned u = ((const unsigned*)p)[elt >> 1];
    return make_float2(lo16(u), hi16(u));
}
__device__ __forceinline__ void ld8(const void* p, int elt, int f32, float* v){
    if (f32){
        const float4* q = (const float4*)((const float*)p + elt);
        float4 a = q[0], b = q[1];
        v[0]=a.x; v[1]=a.y; v[2]=a.z; v[3]=a.w; v[4]=b.x; v[5]=b.y; v[6]=b.z; v[7]=b.w;
    } else {
        uint4 u = *(const uint4*)((const bf16*)p + elt);
        v[0]=lo16(u.x); v[1]=hi16(u.x); v[2]=lo16(u.y); v[3]=hi16(u.y);
        v[4]=lo16(u.z); v[5]=hi16(u.z); v[6]=lo16(u.w); v[7]=hi16(u.w);
    }
}
__device__ __forceinline__ void st_out(void* o, int i, int f32, float v){
    if (f32) ((float*)o)[i] = v; else ((bf16*)o)[i] = __float2bfloat16(v);
}

__global__ __launch_bounds__(256) void k_fused(
    const void* __restrict__ seq, const void* __restrict__ mask, const void* __restrict__ stat,
    const void* __restrict__ bank_keys, const void* __restrict__ bank_values,
    const int* __restrict__ cand32,
    const void* __restrict__ W_seq, const void* __restrict__ W_stat, const void* __restrict__ b_enc,
    const void* __restrict__ W_q, const void* __restrict__ b_q,
    const void* __restrict__ proto,
    const void* __restrict__ W_tr, const void* __restrict__ b_tr,
    const void* __restrict__ W_gate, const void* __restrict__ b_gate,
    const void* __restrict__ W_out, const void* __restrict__ b_out,
    const void* __restrict__ W_quant, const void* __restrict__ b_quant,
    const void* __restrict__ W_ev, const void* __restrict__ b_ev,
    void* __restrict__ out)
{
    const int b = blockIdx.x, t = threadIdx.x;
    const int w = t >> 6, lane = t & 63;
    const int h0 = 2*t, h1 = 2*t + 1;
    const int f32 = (((const unsigned short*)mask)[0] == 0) ? 1 : 0;
    const int c64 = ((cand32[1] | cand32[3] | cand32[5] | cand32[7]) == 0) ? 1 : 0;

    __shared__ __align__(16) float s_pool[16];
    __shared__ __align__(16) float s_stat[8];
    __shared__ __align__(16) float g[1536];
    __shared__ __align__(16) float s_q[Hn];
    __shared__ __align__(16) float s_sim[Cn];
    __shared__ __align__(16) float f1[Hn];
    __shared__ __align__(16) float f2[Hn];
    __shared__ float s_part[4], s_ss;
    __shared__ float s_bv[4]; __shared__ int s_bi[4];
    __shared__ float s_topv[Kn]; __shared__ int s_sel[Kn];
    __shared__ float s_w[Kn];
    __shared__ float s_score[8], s_pw[8];
    __shared__ float s_head[8][4];

    if (t < 16) {
        float acc = 0.f, ms = 0.f;
        for (int l = 0; l < 64; l++) {
            float m = lds_f(mask, b*64 + l, f32);
            ms  += m;
            acc += lds_f(seq, (b*64 + l)*16 + t, f32) * m;
        }
        s_pool[t] = acc / fmaxf(ms, 1e-6f);
    } else if (t < 24) {
        s_stat[t - 16] = lds_f(stat, b*8 + (t - 16), f32);
    }
    __syncthreads();
    {
        float a0 = lds_f(b_enc, h0, f32), a1 = lds_f(b_enc, h1, f32);
        #pragma unroll
        for (int j = 0; j < 16; j++) {
            float2 wv = ldpair(W_seq, j*Hn + h0, f32);
            a0 += s_pool[j]*wv.x; a1 += s_pool[j]*wv.y;
        }
        #pragma unroll
        for (int j = 0; j < 8; j++) {
            float2 wv = ldpair(W_stat, j*Hn + h0, f32);
            a0 += s_stat[j]*wv.x; a1 += s_stat[j]*wv.y;
        }
        a0 = fmaxf(a0, 0.f); a1 = fmaxf(a1, 0.f);
        g[h0] = a0; g[h1] = a1;
    }
    __syncthreads();
    {
        float q0 = lds_f(b_q, h0, f32), q1 = lds_f(b_q, h1, f32);
        #pragma unroll 4
        for (int j = 0; j < Hn; j++) {
            float lj = g[j];
            float2 wv = ldpair(W_q, j*Hn + h0, f32);
            q0 += lj*wv.x; q1 += lj*wv.y;
        }
        float ss = q0*q0 + q1*q1;
        #pragma unroll
        for (int o = 32; o; o >>= 1) ss += __shfl_xor(ss, o);
        if (lane == 0) s_part[w] = ss;
        __syncthreads();
        if (t == 0) s_ss = s_part[0] + s_part[1] + s_part[2] + s_part[3];
        __syncthreads();
        float inv = 1.f / fmaxf(sqrtf(s_ss), 1e-12f);
        s_q[h0] = q0*inv; s_q[h1] = q1*inv;
    }
    __syncthreads();
    float qv[8];
    #pragma unroll
    for (int i = 0; i < 8; i++) qv[i] = s_q[lane*8 + i];

    for (int c0 = w*256; c0 < w*256 + 256; c0 += 4) {
        float kf[4][8];
        #pragma unroll
        for (int u = 0; u < 4; u++) {
            int id = clamp_id(cand32[(size_t)(b*Cn + c0 + u) << c64]);
            ld8(bank_keys, id*Hn + lane*8, f32, kf[u]);
        }
        #pragma unroll
        for (int u = 0; u < 4; u++) {
            float s = 0.f;
            #pragma unroll
            for (int i = 0; i < 8; i++) s += kf[u][i]*qv[i];
            #pragma unroll
            for (int o = 32; o; o >>= 1) s += __shfl_xor(s, o);
            if (lane == 0) s_sim[c0 + u] = s;
        }
    }
    __syncthreads();
    for (int k = 0; k < Kn; k++) {
        float best = -1e30f; int bi = 0x7fffffff;
        for (int i = t; i < Cn; i += 256) {
            float v = s_sim[i];
            if (v > best || (v == best && i < bi)) { best = v; bi = i; }
        }
        #pragma unroll
        for (int o = 32; o; o >>= 1) {
            float ov = __shfl_xor(best, o); int oi = __shfl_xor(bi, o);
            if (ov > best || (ov == best && oi < bi)) { best = ov; bi = oi; }
        }
        if (lane == 0) { s_bv[w] = best; s_bi[w] = bi; }
        __syncthreads();
        if (t == 0) {
            float bv = s_bv[0]; int bbi = s_bi[0];
            for (int x = 1; x < 4; x++)
                if (s_bv[x] > bv || (s_bv[x] == bv && s_bi[x] < bbi)) { bv = s_bv[x]; bbi = s_bi[x]; }
            if (bbi < 0 || bbi >= Cn) bbi = 0;
            s_topv[k] = bv; s_sel[k] = bbi; s_sim[bbi] = -1e30f;
        }
        __syncthreads();
    }
    if (t == 0) {
        float m = s_topv[0];
        float e[Kn], ssum = 0.f;
        for (int k = 0; k < Kn; k++) { e[k] = __expf((s_topv[k] - m) * 5.0f); ssum += e[k]; }
        float inv = 1.f / ssum;
        for (int k = 0; k < Kn; k++) s_w[k] = e[k] * inv;
    }
    __syncthreads();
    {
        float a0 = 0.f, a1 = 0.f;
        #pragma unroll
        for (int k = 0; k < Kn; k++) {
            int id = clamp_id(cand32[(size_t)(b*Cn + s_sel[k]) << c64]);
            float2 v = ldpair(bank_values, id*Hn + h0, f32);
            a0 += s_w[k]*v.x; a1 += s_w[k]*v.y;
        }
        g[512 + h0] = a0; g[512 + h1] = a1;
    }
    for (int p = w; p < 8; p += 4) {
        float f[8];
        ld8(proto, p*Hn + lane*8, f32, f);
        float dq = 0.f, sq = 0.f;
        #pragma unroll
        for (int i = 0; i < 8; i++) { dq += f[i]*qv[i]; sq += f[i]*f[i]; }
        #pragma unroll
        for (int o = 32; o; o >>= 1) { dq += __shfl_xor(dq, o); sq += __shfl_xor(sq, o); }
        if (lane == 0) s_score[p] = dq / fmaxf(sqrtf(sq), 1e-12f);
    }
    __syncthreads();
    if (t == 0) {
        float m = s_score[0];
        for (int p = 1; p < 8; p++) m = fmaxf(m, s_score[p]);
        float e[8], ssum = 0.f;
        for (int p = 0; p < 8; p++) { e[p] = __expf(s_score[p] - m); ssum += e[p]; }
        float inv = 1.f / ssum;
        for (int p = 0; p < 8; p++) s_pw[p] = e[p] * inv;
    }
    __syncthreads();
    {
        float a0 = 0.f, a1 = 0.f;
        #pragma unroll
        for (int p = 0; p < 8; p++) {
            float2 v = ldpair(proto, p*Hn + h0, f32);
            a0 += s_pw[p]*v.x; a1 += s_pw[p]*v.y;
        }
        g[1024 + h0] = a0; g[1024 + h1] = a1;
    }
    __syncthreads();
    float tr0 = lds_f(b_tr, h0, f32), tr1 = lds_f(b_tr, h1, f32);
    #pragma unroll 4
    for (int j = 0; j < 1024; j++) {
        float gj = g[512 + j];
        float2 wv = ldpair(W_tr, j*Hn + h0, f32);
        tr0 += gj*wv.x; tr1 += gj*wv.y;
    }
    tr0 = fmaxf(tr0, 0.f); tr1 = fmaxf(tr1, 0.f);
    float gt0 = lds_f(b_gate, h0, f32), gt1 = lds_f(b_gate, h1, f32);
    #pragma unroll 4
    for (int j = 0; j < 1536; j++) {
        float gj = g[j];
        float2 wv = ldpair(W_gate, j*Hn + h0, f32);
        gt0 += gj*wv.x; gt1 += gj*wv.y;
    }
    gt0 = 1.f/(1.f + __expf(-gt0)); gt1 = 1.f/(1.f + __expf(-gt1));
    f1[h0] = gt0*g[h0] + (1.f - gt0)*tr0;
    f1[h1] = gt1*g[h1] + (1.f - gt1)*tr1;
    __syncthreads();
    {
        float o0 = lds_f(b_out, h0, f32), o1 = lds_f(b_out, h1, f32);
        #pragma unroll 4
        for (int j = 0; j < Hn; j++) {
            float fj = f1[j];
            float2 wv = ldpair(W_out, j*Hn + h0, f32);
            o0 += fj*wv.x; o1 += fj*wv.y;
        }
        o0 = fmaxf(o0, 0.f); o1 = fmaxf(o1, 0.f);
        f2[h0] = o0; f2[h1] = o1;
    }
    __syncthreads();
    {
        float acc[8];
        #pragma unroll
        for (int o = 0; o < 8; o++) acc[o] = 0.f;
        for (int h = t; h < Hn; h += 256) {
            float fh = f2[h];
            acc[0] += fh*lds_f(W_quant, (0*Hn + h)*3 + 0, f32);
            acc[1] += fh*lds_f(W_quant, (0*Hn + h)*3 + 1, f32);
            acc[2] += fh*lds_f(W_quant, (0*Hn + h)*3 + 2, f32);
            acc[3] += fh*lds_f(W_quant, (1*Hn + h)*3 + 0, f32);
            acc[4] += fh*lds_f(W_quant, (1*Hn + h)*3 + 1, f32);
            acc[5] += fh*lds_f(W_quant, (1*Hn + h)*3 + 2, f32);
            acc[6] += fh*lds_f(W_ev, 0*Hn + h, f32);
            acc[7] += fh*lds_f(W_ev, 1*Hn + h, f32);
        }
        #pragma unroll
        for (int o = 0; o < 8; o++) {
            float v = acc[o];
            #pragma unroll
            for (int s = 32; s; s >>= 1) v += __shfl_xor(v, s);
            if (lane == 0) s_head[o][w] = v;
        }
        __syncthreads();
        if (t == 0) {
            float q[6];
            for (int o = 0; o < 6; o++)
                q[o] = s_head[o][0] + s_head[o][1] + s_head[o][2] + s_head[o][3] + lds_f(b_quant, o, f32);
            #pragma unroll
            for (int tt = 0; tt < 2; tt++) {
                float a = q[tt*3], bb = q[tt*3+1], c = q[tt*3+2];
                float mn = fminf(a, fminf(bb, c)), mx = fmaxf(a, fmaxf(bb, c));
                float md = a + bb + c - mn - mx;
                q[tt*3] = mn; q[tt*3+1] = md; q[tt*3+2] = mx;
            }
            for (int o = 0; o < 6; o++) st_out(out, b*8 + o, f32, q[o]);
            float l0 = s_head[6][0] + s_head[6][1] + s_head[6][2] + s_head[6][3] + lds_f(b_ev, 0, f32);
            float l1 = s_head[7][0] + s_head[7][1] + s_head[7][2] + s_head[7][3] + lds_f(b_ev, 1, f32);
            st_out(out, b*8 + 6, f32, l0);
            st_out(out, b*8 + 7, f32, l1);
        }
    }
}

extern "C" void kernel_launch(void* const* d_in, const int* in_sizes, int n_in,
                              void* d_out, int out_size, void* d_ws, size_t ws_size,
                              hipStream_t stream) {
    static const int expect[22] = {
        512*64*16, 512*64, 512*8, 50000*512, 50000*512, 512*1024,
        16*512, 8*512, 512, 512*512, 512, 8*512,
        1024*512, 512, 1536*512, 512, 512*512, 512,
        2*512*3, 2*3, 2*512, 2
    };
    if (n_in != 22 || out_size != 512*8) return;
    for (int i = 0; i < 22; i++) if (in_sizes[i] != expect[i]) return;

    if (ws_size < (size_t)WS_FLOATS * 4) {
        k_fused<<<Bn, 256, 0, stream>>>(
            d_in[0], d_in[1], d_in[2], d_in[3], d_in[4], (const int*)d_in[5],
            d_in[6], d_in[7], d_in[8], d_in[9], d_in[10], d_in[11],
            d_in[12], d_in[13], d_in[14], d_in[15], d_in[16], d_in[17],
            d_in[18], d_in[19], d_in[20], d_in[21], d_out);
        return;
    }

    float* ws = (float*)d_ws;
    int* iws = (int*)(ws + F_OFF);
    int* hist   = iws + HIST_I;
    int* cursor = iws + CURSOR_I;
    int* gtot   = iws + GTOT_I;
    int* offs   = iws + OFFS_I;
    unsigned* refs = (unsigned*)(ws + C_OFF);   // 524288 u32 (C+D slabs, dead until k_select)

    // single memset: hist + cursor + gtot
    hipMemsetAsync(iws, 0, (size_t)(2*NIDPAD + 256)*4, stream);

    k_enc<<<Bn, 256, 0, stream>>>((const float*)d_in[0], (const float*)d_in[1],
                                  (const float*)d_in[2], (const float*)d_in[6],
                                  (const float*)d_in[7], (const float*)d_in[8],
                                  (const int*)d_in[5], ws);
    k_scan<<<NIDPAD/256, 256, 0, stream>>>(hist, offs, gtot);
    k_scatter<<<(Bn*Cn)/256, 256, 0, stream>>>((const int*)d_in[5], cursor, offs, refs);
    k_qgemm_p<<<dim3(8, 8, 4), 256, 0, stream>>>(
        (const float*)d_in[9], (const float*)d_in[10], ws + B_OFF,
        ws + A_OFF, ws + ELO_OFF, ws + EHI_OFF, ws + G_OFF2);
    k_qnorm<<<Bn/4, 256, 0, stream>>>(ws);
    k_dotinv<<<NBANK/4, 256, 0, stream>>>((const float*)d_in[3], refs, offs, hist, ws);
    k_select<<<Bn, 256, 0, stream>>>((const float*)d_in[4], (const int*)d_in[5],
                                     (const float*)d_in[11], ws);
    k_gatetr_p<<<dim3(4, 16, 5), 256, 0, stream>>>(
        (const float*)d_in[12], (const float*)d_in[13],
        (const float*)d_in[14], (const float*)d_in[15], ws);
    k_f1ew<<<256, 256, 0, stream>>>(ws);
    k_qgemm_p<<<dim3(8, 8, 4), 256, 0, stream>>>(
        (const float*)d_in[16], (const float*)d_in[17], ws + A_OFF,
        ws + ELO_OFF, ws + EHI_OFF, ws + F_OFF, ws + G_OFF2);
    k_heads<<<Bn, 64, 0, stream>>>((const float*)d_in[18], (const float*)d_in[19],
                                   (const float*)d_in[20], (const float*)d_in[21],
                                   ws, (float*)d_out);
}

// Round 3
// 500.413 us; speedup vs baseline: 1.0927x; 1.0153x over previous
//
#include <hip/hip_runtime.h>
#include <hip/hip_bf16.h>

typedef __hip_bfloat16 bf16;
typedef float f4v __attribute__((ext_vector_type(4)));
typedef float f2v __attribute__((ext_vector_type(2)));

__device__ __forceinline__ float lo16(unsigned u){ return __uint_as_float(u << 16); }
__device__ __forceinline__ float hi16(unsigned u){ return __uint_as_float(u & 0xffff0000u); }

// B=512, L=64, DDYN=16, DSTAT=8, H=512, C=1024, K=16, P=8, T=2, Q=3
#define Bn 512
#define Hn 512
#define Cn 1024
#define Kn 16
#define NBANK 50000
#define NIDPAD 50176   // 196*256

__device__ __forceinline__ int clamp_id(int id){
    return (id < 0) ? 0 : ((id >= NBANK) ? (NBANK - 1) : id);
}

// ---------------- ws layout (floats), 8 MB total ----------------
// A    @0        : qGEMM partial0 -> QRAW(normed) -> gate partial0 -> F1
// B    @262144   : LOCAL
// C    @524288   : refs.lo -> DONOR
// D    @786432   : refs.hi -> PROTO
// E.lo @1048576  : qGEMM partial1 -> SIM.lo -> gate partial1 -> f2 partial0
// E.hi @1310720  : qGEMM partial2 -> SIM.hi -> gate partial2 -> f2 partial1
// F    @1572864  : ints(hist/cursor/gtot/offs) -> tr partial0 -> f2 partial2
// G    @1835008  : qGEMM partial3 -> tr partial1 -> f2 partial3
#define A_OFF    0
#define B_OFF    262144
#define C_OFF    524288
#define D_OFF    786432
#define SIM_OFF  1048576
#define ELO_OFF  1048576
#define EHI_OFF  1310720
#define F_OFF    1572864
#define G_OFF2   1835008
#define WS_FLOATS 2097152

// int offsets within F region (as int*)
#define HIST_I   0
#define CURSOR_I NIDPAD
#define GTOT_I   (2*NIDPAD)
#define OFFS_I   (2*NIDPAD + 256)   // total ints used: 3*NIDPAD+256 < 262144

// ============ K1: encoder -> LOCAL slab; fused candidate histogram ============
__global__ __launch_bounds__(256) void k_enc(
    const float* __restrict__ seq, const float* __restrict__ mask, const float* __restrict__ stat,
    const float* __restrict__ W_seq, const float* __restrict__ W_stat, const float* __restrict__ b_enc,
    const int* __restrict__ cand32, float* __restrict__ ws)
{
    const int b = blockIdx.x, t = threadIdx.x;
    const int h0 = 2*t, h1 = 2*t + 1;

    {   // histogram of this row's 1024 candidate ids
        const int c64 = ((cand32[1] | cand32[3] | cand32[5] | cand32[7]) == 0) ? 1 : 0;
        int* hist = (int*)(ws + F_OFF) + HIST_I;
        #pragma unroll
        for (int u = 0; u < 4; u++) {
            int idx = b*Cn + u*256 + t;
            atomicAdd(&hist[clamp_id(cand32[(size_t)idx << c64])], 1);
        }
    }

    __shared__ float s_pool[16], s_stat[8];
    if (t < 16) {
        float acc = 0.f, ms = 0.f;
        for (int l = 0; l < 64; l++) {
            float m = mask[b*64 + l];
            ms  += m;
            acc += seq[(b*64 + l)*16 + t] * m;
        }
        s_pool[t] = acc / fmaxf(ms, 1e-6f);
    } else if (t < 24) {
        s_stat[t - 16] = stat[b*8 + (t - 16)];
    }
    __syncthreads();
    float a0 = b_enc[h0], a1 = b_enc[h1];
    #pragma unroll
    for (int j = 0; j < 16; j++) {
        float2 wv = *(const float2*)(W_seq + j*Hn + h0);
        a0 += s_pool[j]*wv.x; a1 += s_pool[j]*wv.y;
    }
    #pragma unroll
    for (int j = 0; j < 8; j++) {
        float2 wv = *(const float2*)(W_stat + j*Hn + h0);
        a0 += s_stat[j]*wv.x; a1 += s_stat[j]*wv.y;
    }
    float* g = ws + B_OFF + (size_t)b*Hn;
    g[h0] = fmaxf(a0, 0.f); g[h1] = fmaxf(a1, 0.f);
}

// ============ K2: fused scan — per-chunk exclusive scan + atomic chunk base ============
__global__ __launch_bounds__(256) void k_scan(
    const int* __restrict__ hist, int* __restrict__ offs, int* __restrict__ gtot)
{
    __shared__ int s[256]; __shared__ int sbase;
    const int t = threadIdx.x, g = blockIdx.x*256 + t;
    const int v = hist[g];
    s[t] = v; __syncthreads();
    #pragma unroll
    for (int off = 1; off < 256; off <<= 1) {
        int x = (t >= off) ? s[t - off] : 0;
        __syncthreads();
        s[t] += x;
        __syncthreads();
    }
    if (t == 255) sbase = atomicAdd(gtot, s[255]);
    __syncthreads();
    offs[g] = sbase + s[t] - v;   // absolute exclusive offset (chunk order arbitrary)
}

// ============ K3: scatter (b,c) refs into id buckets ============
__global__ __launch_bounds__(256) void k_scatter(
    const int* __restrict__ cand32, int* __restrict__ cursor,
    const int* __restrict__ offs, unsigned* __restrict__ refs)
{
    const int i = blockIdx.x*256 + threadIdx.x;   // i = b*1024 + c
    const int c64 = ((cand32[1] | cand32[3] | cand32[5] | cand32[7]) == 0) ? 1 : 0;
    const int id = clamp_id(cand32[(size_t)i << c64]);
    const int pos = atomicAdd(&cursor[id], 1);
    refs[offs[id] + pos] = (unsigned)i;
}

// ============ K4: GEMM 512x512x512, split-K to 4 partial buffers (no atomics) ============
// grid (8 ct, 8 rt, 4 kz); tile 64r x 64c, K-slice 128; thread 4r x 4c
__global__ __launch_bounds__(256) void k_qgemm_p(
    const float* __restrict__ W, const float* __restrict__ bias,
    const float* __restrict__ in,
    float* __restrict__ P0, float* __restrict__ P1,
    float* __restrict__ P2, float* __restrict__ P3)
{
    const int ct = blockIdx.x, rt = blockIdx.y, kz = blockIdx.z, t = threadIdx.x;
    __shared__ float lt[64][132];
    {   // stage 64 rows x 128 k
        int r = t >> 2, c0 = (t & 3)*32;
        const float* src = in + (size_t)(rt*64 + r)*Hn + kz*128 + c0;
        #pragma unroll
        for (int i = 0; i < 8; i++)
            *(float4*)&lt[r][c0 + i*4] = *(const float4*)(src + i*4);
    }
    __syncthreads();
    const int col0 = ct*64 + (t & 15)*4, rbase = (t >> 4)*4;
    float acc[4][4];
    if (kz == 0) {
        float4 bv = *(const float4*)(bias + col0);
        #pragma unroll
        for (int i = 0; i < 4; i++) { acc[i][0]=bv.x; acc[i][1]=bv.y; acc[i][2]=bv.z; acc[i][3]=bv.w; }
    } else {
        #pragma unroll
        for (int i = 0; i < 4; i++) { acc[i][0]=0; acc[i][1]=0; acc[i][2]=0; acc[i][3]=0; }
    }
    const float* wp = W + (size_t)(kz*128)*Hn + col0;
    #pragma unroll 4
    for (int k = 0; k < 128; k++) {
        float4 wv = *(const float4*)(wp + (size_t)k*Hn);
        #pragma unroll
        for (int i = 0; i < 4; i++) {
            float a = lt[rbase + i][k];
            acc[i][0] += a*wv.x; acc[i][1] += a*wv.y; acc[i][2] += a*wv.z; acc[i][3] += a*wv.w;
        }
    }
    float* outp = (kz == 0) ? P0 : (kz == 1) ? P1 : (kz == 2) ? P2 : P3;
    #pragma unroll
    for (int i = 0; i < 4; i++) {
        float* op = outp + (size_t)(rt*64 + rbase + i)*Hn + col0;
        *(float4*)op = make_float4(acc[i][0], acc[i][1], acc[i][2], acc[i][3]);
    }
}

// ============ K5: sum 4 q-partials + normalize -> QRAW (A) ============
__global__ __launch_bounds__(256) void k_qnorm(float* __restrict__ ws)
{
    const int b = blockIdx.x*4 + (threadIdx.x >> 6), lane = threadIdx.x & 63;
    const size_t o = (size_t)b*Hn + lane*8;
    const float* p0 = ws + A_OFF   + o;
    const float* p1 = ws + ELO_OFF + o;
    const float* p2 = ws + EHI_OFF + o;
    const float* p3 = ws + G_OFF2  + o;
    float4 qa, qb;
    {
        float4 a0 = *(const float4*)p0, a1 = *(const float4*)p1,
               a2 = *(const float4*)p2, a3 = *(const float4*)p3;
        qa = make_float4(((a0.x+a1.x)+a2.x)+a3.x, ((a0.y+a1.y)+a2.y)+a3.y,
                         ((a0.z+a1.z)+a2.z)+a3.z, ((a0.w+a1.w)+a2.w)+a3.w);
        float4 b0 = *(const float4*)(p0+4), b1 = *(const float4*)(p1+4),
               b2 = *(const float4*)(p2+4), b3 = *(const float4*)(p3+4);
        qb = make_float4(((b0.x+b1.x)+b2.x)+b3.x, ((b0.y+b1.y)+b2.y)+b3.y,
                         ((b0.z+b1.z)+b2.z)+b3.z, ((b0.w+b1.w)+b2.w)+b3.w);
    }
    float ss = qa.x*qa.x + qa.y*qa.y + qa.z*qa.z + qa.w*qa.w
             + qb.x*qb.x + qb.y*qb.y + qb.z*qb.z + qb.w*qb.w;
    #pragma unroll
    for (int o2 = 32; o2; o2 >>= 1) ss += __shfl_xor(ss, o2);
    float inv = 1.f / fmaxf(sqrtf(ss), 1e-12f);
    qa.x *= inv; qa.y *= inv; qa.z *= inv; qa.w *= inv;
    qb.x *= inv; qb.y *= inv; qb.z *= inv; qb.w *= inv;
    float* qr = ws + A_OFF + o;
    *(float4*)qr = qa; *(float4*)(qr + 4) = qb;
}

// ============ K6: inverted-index sim — nt key stream, predicated tail, hi-occ ============
// Keys are single-use: non-temporal loads keep QRAW (1 MB) resident in each L2,
// so the 1.07 GB q-gather is served at L2 speed instead of L3.
#define DI_LOAD(R0,R1,R2,R3,A0,Bq0,A1,Bq1,A2,Bq2,A3,Bq3,BASE) do {                       \
    int j0_=(BASE), j1_=(BASE)+1, j2_=(BASE)+2, j3_=(BASE)+3;                            \
    const int m_ = n - 1;                                                                \
    const int c1_ = (j1_ < n), c2_ = (j2_ < n), c3_ = (j3_ < n);                         \
    j0_ = j0_>m_?m_:j0_; j1_ = j1_>m_?m_:j1_; j2_ = j2_>m_?m_:j2_; j3_ = j3_>m_?m_:j3_;  \
    R0 = (j0_<64)?(unsigned)__shfl((int)refv,j0_):__builtin_nontemporal_load(refs+start+j0_); \
    R1 = (j1_<64)?(unsigned)__shfl((int)refv,j1_):__builtin_nontemporal_load(refs+start+j1_); \
    R2 = (j2_<64)?(unsigned)__shfl((int)refv,j2_):__builtin_nontemporal_load(refs+start+j2_); \
    R3 = (j3_<64)?(unsigned)__shfl((int)refv,j3_):__builtin_nontemporal_load(refs+start+j3_); \
    {   const float* q0_ = qbase + (size_t)(R0>>10)*Hn + lane*8;                         \
        A0 = *(const float4*)q0_; Bq0 = *(const float4*)(q0_+4); }                       \
    if (c1_) { const float* q1_ = qbase + (size_t)(R1>>10)*Hn + lane*8;                  \
        A1 = *(const float4*)q1_; Bq1 = *(const float4*)(q1_+4); }                       \
    if (c2_) { const float* q2_ = qbase + (size_t)(R2>>10)*Hn + lane*8;                  \
        A2 = *(const float4*)q2_; Bq2 = *(const float4*)(q2_+4); }                       \
    if (c3_) { const float* q3_ = qbase + (size_t)(R3>>10)*Hn + lane*8;                  \
        A3 = *(const float4*)q3_; Bq3 = *(const float4*)(q3_+4); }                       \
} while(0)

#define DI_COMP(R0,R1,R2,R3,A0,Bq0,A1,Bq1,A2,Bq2,A3,Bq3,BASE) do {                       \
    float s0_ = ka.x*A0.x + ka.y*A0.y + ka.z*A0.z + ka.w*A0.w                            \
              + kb.x*Bq0.x + kb.y*Bq0.y + kb.z*Bq0.z + kb.w*Bq0.w;                       \
    float s1_ = ka.x*A1.x + ka.y*A1.y + ka.z*A1.z + ka.w*A1.w                            \
              + kb.x*Bq1.x + kb.y*Bq1.y + kb.z*Bq1.z + kb.w*Bq1.w;                       \
    float s2_ = ka.x*A2.x + ka.y*A2.y + ka.z*A2.z + ka.w*A2.w                            \
              + kb.x*Bq2.x + kb.y*Bq2.y + kb.z*Bq2.z + kb.w*Bq2.w;                       \
    float s3_ = ka.x*A3.x + ka.y*A3.y + ka.z*A3.z + ka.w*A3.w                            \
              + kb.x*Bq3.x + kb.y*Bq3.y + kb.z*Bq3.z + kb.w*Bq3.w;                       \
    s0_ += __shfl_xor(s0_,32); s1_ += __shfl_xor(s1_,32);                                \
    s2_ += __shfl_xor(s2_,32); s3_ += __shfl_xor(s3_,32);                                \
    s0_ += __shfl_xor(s0_,16); s1_ += __shfl_xor(s1_,16);                                \
    s2_ += __shfl_xor(s2_,16); s3_ += __shfl_xor(s3_,16);                                \
    s0_ += __shfl_xor(s0_, 8); s1_ += __shfl_xor(s1_, 8);                                \
    s2_ += __shfl_xor(s2_, 8); s3_ += __shfl_xor(s3_, 8);                                \
    int d_ = (lane >> 3) & 3;                                                            \
    float t_ = d_==0 ? s0_ : d_==1 ? s1_ : d_==2 ? s2_ : s3_;                            \
    t_ += __shfl_xor(t_, 4); t_ += __shfl_xor(t_, 2); t_ += __shfl_xor(t_, 1);           \
    if ((lane & 7) == 0 && lane < 32) {                                                  \
        int dd_ = lane >> 3;                                                             \
        if ((BASE) + dd_ < n) {                                                          \
            unsigned rs_ = dd_==0 ? R0 : dd_==1 ? R1 : dd_==2 ? R2 : R3;                 \
            simw[rs_] = t_;                                                              \
        }                                                                                \
    }                                                                                    \
} while(0)

__global__ __launch_bounds__(256) void k_dotinv(
    const float* __restrict__ bank_keys, const unsigned* __restrict__ refs,
    const int* __restrict__ offs, const int* __restrict__ cnt,
    float* __restrict__ ws)
{
    const int id = blockIdx.x*4 + (threadIdx.x >> 6);
    const int lane = threadIdx.x & 63;
    const int n = cnt[id];
    if (n <= 0) return;
    const int start = offs[id];

    const float* kp = bank_keys + (size_t)id*Hn + lane*8;
    f4v kav = __builtin_nontemporal_load((const f4v*)kp);
    f4v kbv = __builtin_nontemporal_load((const f4v*)(kp + 4));
    float4 ka = make_float4(kav.x, kav.y, kav.z, kav.w);
    float4 kb = make_float4(kbv.x, kbv.y, kbv.z, kbv.w);
    const unsigned refv = refs[start + (lane < n ? lane : n - 1)];
    const float* qbase = ws + A_OFF;
    float* simw = ws + SIM_OFF;

    unsigned Ar0,Ar1,Ar2,Ar3, Br0=0,Br1=0,Br2=0,Br3=0;
    float4 Aa0,Ab0,Aa1,Ab1,Aa2,Ab2,Aa3,Ab3;
    float4 Ba0,Bb0,Ba1,Bb1,Ba2,Bb2,Ba3,Bb3;
    Aa0=Ab0=Aa1=Ab1=Aa2=Ab2=Aa3=Ab3=make_float4(0.f,0.f,0.f,0.f);
    Ba0=Bb0=Ba1=Bb1=Ba2=Bb2=Ba3=Bb3=make_float4(0.f,0.f,0.f,0.f);

    DI_LOAD(Ar0,Ar1,Ar2,Ar3, Aa0,Ab0,Aa1,Ab1,Aa2,Ab2,Aa3,Ab3, 0);
    for (int base = 0; ; ) {
        if (base + 4 < n) DI_LOAD(Br0,Br1,Br2,Br3, Ba0,Bb0,Ba1,Bb1,Ba2,Bb2,Ba3,Bb3, base + 4);
        DI_COMP(Ar0,Ar1,Ar2,Ar3, Aa0,Ab0,Aa1,Ab1,Aa2,Ab2,Aa3,Ab3, base);
        if (base + 8 < n) DI_LOAD(Ar0,Ar1,Ar2,Ar3, Aa0,Ab0,Aa1,Ab1,Aa2,Ab2,Aa3,Ab3, base + 8);
        DI_COMP(Br0,Br1,Br2,Br3, Ba0,Bb0,Ba1,Bb1,Ba2,Bb2,Ba3,Bb3, base + 4);
        base += 8;
        if (base >= n) break;
    }
}

// ============ K7: top-16 + softmax + donor + proto ============
__global__ __launch_bounds__(256) void k_select(
    const float* __restrict__ bank_values, const int* __restrict__ cand32,
    const float* __restrict__ proto, float* __restrict__ ws)
{
    const int b = blockIdx.x, t = threadIdx.x;
    const int w = t >> 6, lane = t & 63;
    const int h0 = 2*t, h1 = 2*t + 1;
    const int c64 = ((cand32[1] | cand32[3] | cand32[5] | cand32[7]) == 0) ? 1 : 0;

    __shared__ __align__(16) float s_sim[Cn];
    __shared__ float s_bv[4]; __shared__ int s_bi[4];
    __shared__ float s_topv[Kn]; __shared__ int s_sel[Kn];
    __shared__ float s_w[Kn];
    __shared__ float s_score[8], s_pw[8];

    *(float4*)&s_sim[t*4] = *(const float4*)(ws + SIM_OFF + (size_t)b*Cn + t*4);

    const float* qr = ws + A_OFF + (size_t)b*Hn + lane*8;
    float4 qa = *(const float4*)qr, qb = *(const float4*)(qr + 4);
    float qv[8] = {qa.x, qa.y, qa.z, qa.w, qb.x, qb.y, qb.z, qb.w};
    __syncthreads();

    for (int k = 0; k < Kn; k++) {
        float best = -1e30f; int bi = 0x7fffffff;
        for (int i = t; i < Cn; i += 256) {
            float v = s_sim[i];
            if (v > best || (v == best && i < bi)) { best = v; bi = i; }
        }
        #pragma unroll
        for (int o = 32; o; o >>= 1) {
            float ov = __shfl_xor(best, o); int oi = __shfl_xor(bi, o);
            if (ov > best || (ov == best && oi < bi)) { best = ov; bi = oi; }
        }
        if (lane == 0) { s_bv[w] = best; s_bi[w] = bi; }
        __syncthreads();
        if (t == 0) {
            float bv = s_bv[0]; int bbi = s_bi[0];
            for (int x = 1; x < 4; x++)
                if (s_bv[x] > bv || (s_bv[x] == bv && s_bi[x] < bbi)) { bv = s_bv[x]; bbi = s_bi[x]; }
            if (bbi < 0 || bbi >= Cn) bbi = 0;
            s_topv[k] = bv; s_sel[k] = bbi; s_sim[bbi] = -1e30f;
        }
        __syncthreads();
    }

    if (t == 0) {
        float m = s_topv[0];
        float e[Kn], ssum = 0.f;
        for (int k = 0; k < Kn; k++) { e[k] = __expf((s_topv[k] - m) * 5.0f); ssum += e[k]; }
        float inv = 1.f / ssum;
        for (int k = 0; k < Kn; k++) s_w[k] = e[k] * inv;
    }
    for (int p = w; p < 8; p += 4) {
        const float* pp = proto + (size_t)p*Hn + lane*8;
        float4 pa = *(const float4*)pp, pb = *(const float4*)(pp + 4);
        float f[8] = {pa.x, pa.y, pa.z, pa.w, pb.x, pb.y, pb.z, pb.w};
        float dq = 0.f, sq = 0.f;
        #pragma unroll
        for (int i = 0; i < 8; i++) { dq += f[i]*qv[i]; sq += f[i]*f[i]; }
        #pragma unroll
        for (int o = 32; o; o >>= 1) { dq += __shfl_xor(dq, o); sq += __shfl_xor(sq, o); }
        if (lane == 0) s_score[p] = dq / fmaxf(sqrtf(sq), 1e-12f);
    }
    __syncthreads();
    if (t == 0) {
        float m = s_score[0];
        for (int p = 1; p < 8; p++) m = fmaxf(m, s_score[p]);
        float e[8], ssum = 0.f;
        for (int p = 0; p < 8; p++) { e[p] = __expf(s_score[p] - m); ssum += e[p]; }
        float inv = 1.f / ssum;
        for (int p = 0; p < 8; p++) s_pw[p] = e[p] * inv;
    }
    __syncthreads();

    {
        float a0 = 0.f, a1 = 0.f;
        #pragma unroll
        for (int k = 0; k < Kn; k++) {
            int id = clamp_id(cand32[(size_t)(b*Cn + s_sel[k]) << c64]);
            f2v v = __builtin_nontemporal_load((const f2v*)(bank_values + (size_t)id*Hn + h0));
            a0 += s_w[k]*v.x; a1 += s_w[k]*v.y;
        }
        float* gd = ws + C_OFF + (size_t)b*Hn;
        gd[h0] = a0; gd[h1] = a1;
    }
    {
        float a0 = 0.f, a1 = 0.f;
        #pragma unroll
        for (int p = 0; p < 8; p++) {
            float2 v = *(const float2*)(proto + (size_t)p*Hn + h0);
            a0 += s_pw[p]*v.x; a1 += s_pw[p]*v.y;
        }
        float* gp = ws + D_OFF + (size_t)b*Hn;
        gp[h0] = a0; gp[h1] = a1;
    }
}

// ============ K8: gate/tr -> 5 partial buffers (no atomics) ============
// grid (4 ct, 16 rt, 5 z): z<3 gate K-slice z (K=512 = slab z); z>=3 tr slice z-3
// tile 32r x 128c; thread 4r x 4c; K staged in two 256-halves
__global__ __launch_bounds__(256) void k_gatetr_p(
    const float* __restrict__ W_tr, const float* __restrict__ b_tr,
    const float* __restrict__ W_gate, const float* __restrict__ b_gate,
    float* __restrict__ ws)
{
    const int ct = blockIdx.x, rt = blockIdx.y, z = blockIdx.z, t = threadIdx.x;
    const int isGate = (z < 3);
    const int sl = isGate ? z : (z - 3);
    const float* W = isGate ? (W_gate + (size_t)(z*512)*Hn) : (W_tr + (size_t)(sl*512)*Hn);
    const float* slab = ws + B_OFF + (size_t)(isGate ? z : (sl + 1))*262144;
    float* outp = isGate
        ? ((z == 0) ? ws + A_OFF : (z == 1) ? ws + ELO_OFF : ws + EHI_OFF)
        : ((sl == 0) ? ws + F_OFF : ws + G_OFF2);

    __shared__ float lt[32][260];
    const int col0 = ct*128 + (t & 31)*4, rbase = (t >> 5)*4;
    float acc[4][4];
    if (z == 0 || z == 3) {
        const float* bias = isGate ? b_gate : b_tr;
        float4 bv = *(const float4*)(bias + col0);
        #pragma unroll
        for (int i = 0; i < 4; i++) { acc[i][0]=bv.x; acc[i][1]=bv.y; acc[i][2]=bv.z; acc[i][3]=bv.w; }
    } else {
        #pragma unroll
        for (int i = 0; i < 4; i++) { acc[i][0]=0; acc[i][1]=0; acc[i][2]=0; acc[i][3]=0; }
    }

    #pragma unroll
    for (int h = 0; h < 2; h++) {
        if (h) __syncthreads();
        {   // stage 32 rows x 256 k
            int r = t >> 3, c0 = (t & 7)*32;
            const float* src = slab + (size_t)(rt*32 + r)*Hn + h*256 + c0;
            #pragma unroll
            for (int i = 0; i < 8; i++)
                *(float4*)&lt[r][c0 + i*4] = *(const float4*)(src + i*4);
        }
        __syncthreads();
        const float* wp = W + (size_t)(h*256)*Hn + col0;
        #pragma unroll 4
        for (int k = 0; k < 256; k++) {
            float4 wv = *(const float4*)(wp + (size_t)k*Hn);
            #pragma unroll
            for (int i = 0; i < 4; i++) {
                float a = lt[rbase + i][k];
                acc[i][0] += a*wv.x; acc[i][1] += a*wv.y; acc[i][2] += a*wv.z; acc[i][3] += a*wv.w;
            }
        }
    }
    #pragma unroll
    for (int i = 0; i < 4; i++) {
        float* op = outp + (size_t)(rt*32 + rbase + i)*Hn + col0;
        *(float4*)op = make_float4(acc[i][0], acc[i][1], acc[i][2], acc[i][3]);
    }
}

// ============ K9: f1 = sigmoid(Σgate)*local + (1-sig)*relu(Σtr) -> A ============
__global__ __launch_bounds__(256) void k_f1ew(float* __restrict__ ws)
{
    const int i4 = blockIdx.x*256 + threadIdx.x;   // 65536 float4s
    const size_t off = (size_t)(i4 >> 7)*Hn + (i4 & 127)*4;
    float4 lc = *(const float4*)(ws + B_OFF + off);
    float4 g0 = *(const float4*)(ws + A_OFF + off);
    float4 g1 = *(const float4*)(ws + ELO_OFF + off);
    float4 g2 = *(const float4*)(ws + EHI_OFF + off);
    float4 t0 = *(const float4*)(ws + F_OFF + off);
    float4 t1 = *(const float4*)(ws + G_OFF2 + off);
    float4 ga = make_float4((g0.x+g1.x)+g2.x, (g0.y+g1.y)+g2.y,
                            (g0.z+g1.z)+g2.z, (g0.w+g1.w)+g2.w);
    float4 tr = make_float4(t0.x+t1.x, t0.y+t1.y, t0.z+t1.z, t0.w+t1.w);
    float4 r;
    float s;
    s = 1.f/(1.f + __expf(-ga.x)); r.x = s*lc.x + (1.f-s)*fmaxf(tr.x, 0.f);
    s = 1.f/(1.f + __expf(-ga.y)); r.y = s*lc.y + (1.f-s)*fmaxf(tr.y, 0.f);
    s = 1.f/(1.f + __expf(-ga.z)); r.z = s*lc.z + (1.f-s)*fmaxf(tr.z, 0.f);
    s = 1.f/(1.f + __expf(-ga.w)); r.w = s*lc.w + (1.f-s)*fmaxf(tr.w, 0.f);
    *(float4*)(ws + A_OFF + off) = r;
}

// ============ K10: heads (sums 4 f2-partials, relu, project) ============
__global__ __launch_bounds__(64) void k_heads(
    const float* __restrict__ W_quant, const float* __restrict__ b_quant,
    const float* __restrict__ W_ev, const float* __restrict__ b_ev,
    const float* __restrict__ ws_ro, float* __restrict__ out)
{
    const int b = blockIdx.x, lane = threadIdx.x;
    const size_t o = (size_t)b*Hn + lane*8;
    const float* p0 = ws_ro + ELO_OFF + o;
    const float* p1 = ws_ro + EHI_OFF + o;
    const float* p2 = ws_ro + F_OFF + o;
    const float* p3 = ws_ro + G_OFF2 + o;
    float4 a0 = *(const float4*)p0, a1 = *(const float4*)p1,
           a2 = *(const float4*)p2, a3 = *(const float4*)p3;
    float4 b0 = *(const float4*)(p0+4), b1 = *(const float4*)(p1+4),
           b2 = *(const float4*)(p2+4), b3 = *(const float4*)(p3+4);
    float fv[8] = {
        fmaxf(((a0.x+a1.x)+a2.x)+a3.x, 0.f), fmaxf(((a0.y+a1.y)+a2.y)+a3.y, 0.f),
        fmaxf(((a0.z+a1.z)+a2.z)+a3.z, 0.f), fmaxf(((a0.w+a1.w)+a2.w)+a3.w, 0.f),
        fmaxf(((b0.x+b1.x)+b2.x)+b3.x, 0.f), fmaxf(((b0.y+b1.y)+b2.y)+b3.y, 0.f),
        fmaxf(((b0.z+b1.z)+b2.z)+b3.z, 0.f), fmaxf(((b0.w+b1.w)+b2.w)+b3.w, 0.f)};
    float acc[8];
    #pragma unroll
    for (int q = 0; q < 8; q++) acc[q] = 0.f;
    #pragma unroll
    for (int i = 0; i < 8; i++) {
        int h = lane*8 + i;
        float fh = fv[i];
        acc[0] += fh*W_quant[(0*Hn + h)*3 + 0];
        acc[1] += fh*W_quant[(0*Hn + h)*3 + 1];
        acc[2] += fh*W_quant[(0*Hn + h)*3 + 2];
        acc[3] += fh*W_quant[(1*Hn + h)*3 + 0];
        acc[4] += fh*W_quant[(1*Hn + h)*3 + 1];
        acc[5] += fh*W_quant[(1*Hn + h)*3 + 2];
        acc[6] += fh*W_ev[0*Hn + h];
        acc[7] += fh*W_ev[1*Hn + h];
    }
    #pragma unroll
    for (int q = 0; q < 8; q++) {
        #pragma unroll
        for (int s = 32; s; s >>= 1) acc[q] += __shfl_xor(acc[q], s);
    }
    if (lane == 0) {
        float qv[6];
        for (int q = 0; q < 6; q++) qv[q] = acc[q] + b_quant[q];
        #pragma unroll
        for (int tt = 0; tt < 2; tt++) {
            float a = qv[tt*3], bb = qv[tt*3+1], c = qv[tt*3+2];
            float mn = fminf(a, fminf(bb, c)), mx = fmaxf(a, fmaxf(bb, c));
            float md = a + bb + c - mn - mx;
            qv[tt*3] = mn; qv[tt*3+1] = md; qv[tt*3+2] = mx;
        }
        for (int q = 0; q < 6; q++) out[b*8 + q] = qv[q];
        out[b*8 + 6] = acc[6] + b_ev[0];
        out[b*8 + 7] = acc[7] + b_ev[1];
    }
}

// ===================== Fallback: proven R4 fused kernel =====================
__device__ __forceinline__ float lds_f(const void* p, int i, int f32){
    return f32 ? ((const float*)p)[i] : __bfloat162float(((const bf16*)p)[i]);
}
__device__ __forceinline__ float2 ldpair(const void* p, int elt, int f32){
    if (f32) return ((const float2*)p)[elt >> 1];
    unsigned u = ((const unsigned*)p)[elt >> 1];
    return make_float2(lo16(u), hi16(u));
}
__device__ __forceinline__ void ld8(const void* p, int elt, int f32, float* v){
    if (f32){
        const float4* q = (const float4*)((const float*)p + elt);
        float4 a = q[0], b = q[1];
        v[0]=a.x; v[1]=a.y; v[2]=a.z; v[3]=a.w; v[4]=b.x; v[5]=b.y; v[6]=b.z; v[7]=b.w;
    } else {
        uint4 u = *(const uint4*)((const bf16*)p + elt);
        v[0]=lo16(u.x); v[1]=hi16(u.x); v[2]=lo16(u.y); v[3]=hi16(u.y);
        v[4]=lo16(u.z); v[5]=hi16(u.z); v[6]=lo16(u.w); v[7]=hi16(u.w);
    }
}
__device__ __forceinline__ void st_out(void* o, int i, int f32, float v){
    if (f32) ((float*)o)[i] = v; else ((bf16*)o)[i] = __float2bfloat16(v);
}

__global__ __launch_bounds__(256) void k_fused(
    const void* __restrict__ seq, const void* __restrict__ mask, const void* __restrict__ stat,
    const void* __restrict__ bank_keys, const void* __restrict__ bank_values,
    const int* __restrict__ cand32,
    const void* __restrict__ W_seq, const void* __restrict__ W_stat, const void* __restrict__ b_enc,
    const void* __restrict__ W_q, const void* __restrict__ b_q,
    const void* __restrict__ proto,
    const void* __restrict__ W_tr, const void* __restrict__ b_tr,
    const void* __restrict__ W_gate, const void* __restrict__ b_gate,
    const void* __restrict__ W_out, const void* __restrict__ b_out,
    const void* __restrict__ W_quant, const void* __restrict__ b_quant,
    const void* __restrict__ W_ev, const void* __restrict__ b_ev,
    void* __restrict__ out)
{
    const int b = blockIdx.x, t = threadIdx.x;
    const int w = t >> 6, lane = t & 63;
    const int h0 = 2*t, h1 = 2*t + 1;
    const int f32 = (((const unsigned short*)mask)[0] == 0) ? 1 : 0;
    const int c64 = ((cand32[1] | cand32[3] | cand32[5] | cand32[7]) == 0) ? 1 : 0;

    __shared__ __align__(16) float s_pool[16];
    __shared__ __align__(16) float s_stat[8];
    __shared__ __align__(16) float g[1536];
    __shared__ __align__(16) float s_q[Hn];
    __shared__ __align__(16) float s_sim[Cn];
    __shared__ __align__(16) float f1[Hn];
    __shared__ __align__(16) float f2[Hn];
    __shared__ float s_part[4], s_ss;
    __shared__ float s_bv[4]; __shared__ int s_bi[4];
    __shared__ float s_topv[Kn]; __shared__ int s_sel[Kn];
    __shared__ float s_w[Kn];
    __shared__ float s_score[8], s_pw[8];
    __shared__ float s_head[8][4];

    if (t < 16) {
        float acc = 0.f, ms = 0.f;
        for (int l = 0; l < 64; l++) {
            float m = lds_f(mask, b*64 + l, f32);
            ms  += m;
            acc += lds_f(seq, (b*64 + l)*16 + t, f32) * m;
        }
        s_pool[t] = acc / fmaxf(ms, 1e-6f);
    } else if (t < 24) {
        s_stat[t - 16] = lds_f(stat, b*8 + (t - 16), f32);
    }
    __syncthreads();
    {
        float a0 = lds_f(b_enc, h0, f32), a1 = lds_f(b_enc, h1, f32);
        #pragma unroll
        for (int j = 0; j < 16; j++) {
            float2 wv = ldpair(W_seq, j*Hn + h0, f32);
            a0 += s_pool[j]*wv.x; a1 += s_pool[j]*wv.y;
        }
        #pragma unroll
        for (int j = 0; j < 8; j++) {
            float2 wv = ldpair(W_stat, j*Hn + h0, f32);
            a0 += s_stat[j]*wv.x; a1 += s_stat[j]*wv.y;
        }
        a0 = fmaxf(a0, 0.f); a1 = fmaxf(a1, 0.f);
        g[h0] = a0; g[h1] = a1;
    }
    __syncthreads();
    {
        float q0 = lds_f(b_q, h0, f32), q1 = lds_f(b_q, h1, f32);
        #pragma unroll 4
        for (int j = 0; j < Hn; j++) {
            float lj = g[j];
            float2 wv = ldpair(W_q, j*Hn + h0, f32);
            q0 += lj*wv.x; q1 += lj*wv.y;
        }
        float ss = q0*q0 + q1*q1;
        #pragma unroll
        for (int o = 32; o; o >>= 1) ss += __shfl_xor(ss, o);
        if (lane == 0) s_part[w] = ss;
        __syncthreads();
        if (t == 0) s_ss = s_part[0] + s_part[1] + s_part[2] + s_part[3];
        __syncthreads();
        float inv = 1.f / fmaxf(sqrtf(s_ss), 1e-12f);
        s_q[h0] = q0*inv; s_q[h1] = q1*inv;
    }
    __syncthreads();
    float qv[8];
    #pragma unroll
    for (int i = 0; i < 8; i++) qv[i] = s_q[lane*8 + i];

    for (int c0 = w*256; c0 < w*256 + 256; c0 += 4) {
        float kf[4][8];
        #pragma unroll
        for (int u = 0; u < 4; u++) {
            int id = clamp_id(cand32[(size_t)(b*Cn + c0 + u) << c64]);
            ld8(bank_keys, id*Hn + lane*8, f32, kf[u]);
        }
        #pragma unroll
        for (int u = 0; u < 4; u++) {
            float s = 0.f;
            #pragma unroll
            for (int i = 0; i < 8; i++) s += kf[u][i]*qv[i];
            #pragma unroll
            for (int o = 32; o; o >>= 1) s += __shfl_xor(s, o);
            if (lane == 0) s_sim[c0 + u] = s;
        }
    }
    __syncthreads();
    for (int k = 0; k < Kn; k++) {
        float best = -1e30f; int bi = 0x7fffffff;
        for (int i = t; i < Cn; i += 256) {
            float v = s_sim[i];
            if (v > best || (v == best && i < bi)) { best = v; bi = i; }
        }
        #pragma unroll
        for (int o = 32; o; o >>= 1) {
            float ov = __shfl_xor(best, o); int oi = __shfl_xor(bi, o);
            if (ov > best || (ov == best && oi < bi)) { best = ov; bi = oi; }
        }
        if (lane == 0) { s_bv[w] = best; s_bi[w] = bi; }
        __syncthreads();
        if (t == 0) {
            float bv = s_bv[0]; int bbi = s_bi[0];
            for (int x = 1; x < 4; x++)
                if (s_bv[x] > bv || (s_bv[x] == bv && s_bi[x] < bbi)) { bv = s_bv[x]; bbi = s_bi[x]; }
            if (bbi < 0 || bbi >= Cn) bbi = 0;
            s_topv[k] = bv; s_sel[k] = bbi; s_sim[bbi] = -1e30f;
        }
        __syncthreads();
    }
    if (t == 0) {
        float m = s_topv[0];
        float e[Kn], ssum = 0.f;
        for (int k = 0; k < Kn; k++) { e[k] = __expf((s_topv[k] - m) * 5.0f); ssum += e[k]; }
        float inv = 1.f / ssum;
        for (int k = 0; k < Kn; k++) s_w[k] = e[k] * inv;
    }
    __syncthreads();
    {
        float a0 = 0.f, a1 = 0.f;
        #pragma unroll
        for (int k = 0; k < Kn; k++) {
            int id = clamp_id(cand32[(size_t)(b*Cn + s_sel[k]) << c64]);
            float2 v = ldpair(bank_values, id*Hn + h0, f32);
            a0 += s_w[k]*v.x; a1 += s_w[k]*v.y;
        }
        g[512 + h0] = a0; g[512 + h1] = a1;
    }
    for (int p = w; p < 8; p += 4) {
        float f[8];
        ld8(proto, p*Hn + lane*8, f32, f);
        float dq = 0.f, sq = 0.f;
        #pragma unroll
        for (int i = 0; i < 8; i++) { dq += f[i]*qv[i]; sq += f[i]*f[i]; }
        #pragma unroll
        for (int o = 32; o; o >>= 1) { dq += __shfl_xor(dq, o); sq += __shfl_xor(sq, o); }
        if (lane == 0) s_score[p] = dq / fmaxf(sqrtf(sq), 1e-12f);
    }
    __syncthreads();
    if (t == 0) {
        float m = s_score[0];
        for (int p = 1; p < 8; p++) m = fmaxf(m, s_score[p]);
        float e[8], ssum = 0.f;
        for (int p = 0; p < 8; p++) { e[p] = __expf(s_score[p] - m); ssum += e[p]; }
        float inv = 1.f / ssum;
        for (int p = 0; p < 8; p++) s_pw[p] = e[p] * inv;
    }
    __syncthreads();
    {
        float a0 = 0.f, a1 = 0.f;
        #pragma unroll
        for (int p = 0; p < 8; p++) {
            float2 v = ldpair(proto, p*Hn + h0, f32);
            a0 += s_pw[p]*v.x; a1 += s_pw[p]*v.y;
        }
        g[1024 + h0] = a0; g[1024 + h1] = a1;
    }
    __syncthreads();
    float tr0 = lds_f(b_tr, h0, f32), tr1 = lds_f(b_tr, h1, f32);
    #pragma unroll 4
    for (int j = 0; j < 1024; j++) {
        float gj = g[512 + j];
        float2 wv = ldpair(W_tr, j*Hn + h0, f32);
        tr0 += gj*wv.x; tr1 += gj*wv.y;
    }
    tr0 = fmaxf(tr0, 0.f); tr1 = fmaxf(tr1, 0.f);
    float gt0 = lds_f(b_gate, h0, f32), gt1 = lds_f(b_gate, h1, f32);
    #pragma unroll 4
    for (int j = 0; j < 1536; j++) {
        float gj = g[j];
        float2 wv = ldpair(W_gate, j*Hn + h0, f32);
        gt0 += gj*wv.x; gt1 += gj*wv.y;
    }
    gt0 = 1.f/(1.f + __expf(-gt0)); gt1 = 1.f/(1.f + __expf(-gt1));
    f1[h0] = gt0*g[h0] + (1.f - gt0)*tr0;
    f1[h1] = gt1*g[h1] + (1.f - gt1)*tr1;
    __syncthreads();
    {
        float o0 = lds_f(b_out, h0, f32), o1 = lds_f(b_out, h1, f32);
        #pragma unroll 4
        for (int j = 0; j < Hn; j++) {
            float fj = f1[j];
            float2 wv = ldpair(W_out, j*Hn + h0, f32);
            o0 += fj*wv.x; o1 += fj*wv.y;
        }
        o0 = fmaxf(o0, 0.f); o1 = fmaxf(o1, 0.f);
        f2[h0] = o0; f2[h1] = o1;
    }
    __syncthreads();
    {
        float acc[8];
        #pragma unroll
        for (int o = 0; o < 8; o++) acc[o] = 0.f;
        for (int h = t; h < Hn; h += 256) {
            float fh = f2[h];
            acc[0] += fh*lds_f(W_quant, (0*Hn + h)*3 + 0, f32);
            acc[1] += fh*lds_f(W_quant, (0*Hn + h)*3 + 1, f32);
            acc[2] += fh*lds_f(W_quant, (0*Hn + h)*3 + 2, f32);
            acc[3] += fh*lds_f(W_quant, (1*Hn + h)*3 + 0, f32);
            acc[4] += fh*lds_f(W_quant, (1*Hn + h)*3 + 1, f32);
            acc[5] += fh*lds_f(W_quant, (1*Hn + h)*3 + 2, f32);
            acc[6] += fh*lds_f(W_ev, 0*Hn + h, f32);
            acc[7] += fh*lds_f(W_ev, 1*Hn + h, f32);
        }
        #pragma unroll
        for (int o = 0; o < 8; o++) {
            float v = acc[o];
            #pragma unroll
            for (int s = 32; s; s >>= 1) v += __shfl_xor(v, s);
            if (lane == 0) s_head[o][w] = v;
        }
        __syncthreads();
        if (t == 0) {
            float q[6];
            for (int o = 0; o < 6; o++)
                q[o] = s_head[o][0] + s_head[o][1] + s_head[o][2] + s_head[o][3] + lds_f(b_quant, o, f32);
            #pragma unroll
            for (int tt = 0; tt < 2; tt++) {
                float a = q[tt*3], bb = q[tt*3+1], c = q[tt*3+2];
                float mn = fminf(a, fminf(bb, c)), mx = fmaxf(a, fmaxf(bb, c));
                float md = a + bb + c - mn - mx;
                q[tt*3] = mn; q[tt*3+1] = md; q[tt*3+2] = mx;
            }
            for (int o = 0; o < 6; o++) st_out(out, b*8 + o, f32, q[o]);
            float l0 = s_head[6][0] + s_head[6][1] + s_head[6][2] + s_head[6][3] + lds_f(b_ev, 0, f32);
            float l1 = s_head[7][0] + s_head[7][1] + s_head[7][2] + s_head[7][3] + lds_f(b_ev, 1, f32);
            st_out(out, b*8 + 6, f32, l0);
            st_out(out, b*8 + 7, f32, l1);
        }
    }
}

extern "C" void kernel_launch(void* const* d_in, const int* in_sizes, int n_in,
                              void* d_out, int out_size, void* d_ws, size_t ws_size,
                              hipStream_t stream) {
    static const int expect[22] = {
        512*64*16, 512*64, 512*8, 50000*512, 50000*512, 512*1024,
        16*512, 8*512, 512, 512*512, 512, 8*512,
        1024*512, 512, 1536*512, 512, 512*512, 512,
        2*512*3, 2*3, 2*512, 2
    };
    if (n_in != 22 || out_size != 512*8) return;
    for (int i = 0; i < 22; i++) if (in_sizes[i] != expect[i]) return;

    if (ws_size < (size_t)WS_FLOATS * 4) {
        k_fused<<<Bn, 256, 0, stream>>>(
            d_in[0], d_in[1], d_in[2], d_in[3], d_in[4], (const int*)d_in[5],
            d_in[6], d_in[7], d_in[8], d_in[9], d_in[10], d_in[11],
            d_in[12], d_in[13], d_in[14], d_in[15], d_in[16], d_in[17],
            d_in[18], d_in[19], d_in[20], d_in[21], d_out);
        return;
    }

    float* ws = (float*)d_ws;
    int* iws = (int*)(ws + F_OFF);
    int* hist   = iws + HIST_I;
    int* cursor = iws + CURSOR_I;
    int* gtot   = iws + GTOT_I;
    int* offs   = iws + OFFS_I;
    unsigned* refs = (unsigned*)(ws + C_OFF);   // 524288 u32 (C+D slabs, dead until k_select)

    // single memset: hist + cursor + gtot
    hipMemsetAsync(iws, 0, (size_t)(2*NIDPAD + 256)*4, stream);

    k_enc<<<Bn, 256, 0, stream>>>((const float*)d_in[0], (const float*)d_in[1],
                                  (const float*)d_in[2], (const float*)d_in[6],
                                  (const float*)d_in[7], (const float*)d_in[8],
                                  (const int*)d_in[5], ws);
    k_scan<<<NIDPAD/256, 256, 0, stream>>>(hist, offs, gtot);
    k_scatter<<<(Bn*Cn)/256, 256, 0, stream>>>((const int*)d_in[5], cursor, offs, refs);
    k_qgemm_p<<<dim3(8, 8, 4), 256, 0, stream>>>(
        (const float*)d_in[9], (const float*)d_in[10], ws + B_OFF,
        ws + A_OFF, ws + ELO_OFF, ws + EHI_OFF, ws + G_OFF2);
    k_qnorm<<<Bn/4, 256, 0, stream>>>(ws);
    k_dotinv<<<NBANK/4, 256, 0, stream>>>((const float*)d_in[3], refs, offs, hist, ws);
    k_select<<<Bn, 256, 0, stream>>>((const float*)d_in[4], (const int*)d_in[5],
                                     (const float*)d_in[11], ws);
    k_gatetr_p<<<dim3(4, 16, 5), 256, 0, stream>>>(
        (const float*)d_in[12], (const float*)d_in[13],
        (const float*)d_in[14], (const float*)d_in[15], ws);
    k_f1ew<<<256, 256, 0, stream>>>(ws);
    k_qgemm_p<<<dim3(8, 8, 4), 256, 0, stream>>>(
        (const float*)d_in[16], (const float*)d_in[17], ws + A_OFF,
        ws + ELO_OFF, ws + EHI_OFF, ws + F_OFF, ws + G_OFF2);
    k_heads<<<Bn, 64, 0, stream>>>((const float*)d_in[18], (const float*)d_in[19],
                                   (const float*)d_in[20], (const float*)d_in[21],
                                   ws, (float*)d_out);
}